// Round 5
// baseline (216.949 us; speedup 1.0000x reference)
//
#include <hip/hip_runtime.h>
#include <hip/hip_bf16.h>

#define NN 4096
#define FIN 512
#define FOUT 64
#define NH 8
#define ALPHA 0.2f

typedef unsigned int uint;
typedef unsigned short ushort;
typedef unsigned char uchar;
typedef unsigned long long ull;
typedef __attribute__((ext_vector_type(8))) short short8;
typedef __attribute__((ext_vector_type(4))) float floatx4;

__device__ __forceinline__ float bf2f(ushort s) { return __uint_as_float(((uint)s) << 16); }
__device__ __forceinline__ ushort f2bf(float f) {
    uint u = __float_as_uint(f);
    u += 0x7fffu + ((u >> 16) & 1u);   // RNE
    return (ushort)(u >> 16);
}

// inline dtype probe: wave-uniform, deterministic (same 64 samples everywhere)
__device__ __forceinline__ int detect_bf16(const ushort* __restrict__ hraw) {
    int lane = threadIdx.x & 63;
    float a = fabsf(bf2f(hraw[2 * lane]));
    ull bal = __ballot(a >= 1e-3f && a <= 100.0f);
    return __popcll(bal) >= 32;
}

// ---------------------------------------------------------------------------
// Fused prep: [0,8192) packmask | [8192,9216) convert h (8 elem/thread) |
//             [9216,9248) transw   (unchanged from passing rounds)
// ---------------------------------------------------------------------------
#define PM_BLKS 8192
#define CV_BLKS 1024
#define TW_BLKS 32

__global__ __launch_bounds__(256) void prep_kernel(
    const int* __restrict__ mask, uchar* __restrict__ mb,
    const void* __restrict__ hraw, ushort* __restrict__ bh,
    const void* __restrict__ Wraw, ushort* __restrict__ WT)
{
    const int b = blockIdx.x, t = threadIdx.x;
    if (b < PM_BLKS) {
        size_t gid = (size_t)b * 256 + t;
        const int* p = mask + gid * 8;
        int4 aa = *(const int4*)p;
        int4 bb = *(const int4*)(p + 4);
        uint by = (uint)(aa.x > 0)        | ((uint)(aa.y > 0) << 1)
                | ((uint)(aa.z > 0) << 2) | ((uint)(aa.w > 0) << 3)
                | ((uint)(bb.x > 0) << 4) | ((uint)(bb.y > 0) << 5)
                | ((uint)(bb.z > 0) << 6) | ((uint)(bb.w > 0) << 7);
        mb[gid] = (uchar)by;
    } else if (b < PM_BLKS + CV_BLKS) {
        int isbf = detect_bf16((const ushort*)hraw);
        size_t e0 = ((size_t)(b - PM_BLKS) * 256 + t) * 8;
        if (isbf) {
            *(uint4*)(bh + e0) = *(const uint4*)((const ushort*)hraw + e0);
        } else {
            const float* s = (const float*)hraw + e0;
            float4 f0 = *(const float4*)s;
            float4 f1 = *(const float4*)(s + 4);
            uint4 o;
            o.x = (uint)f2bf(f0.x) | ((uint)f2bf(f0.y) << 16);
            o.y = (uint)f2bf(f0.z) | ((uint)f2bf(f0.w) << 16);
            o.z = (uint)f2bf(f1.x) | ((uint)f2bf(f1.y) << 16);
            o.w = (uint)f2bf(f1.z) | ((uint)f2bf(f1.w) << 16);
            *(uint4*)(bh + e0) = o;
        }
    } else {
        int isbf = detect_bf16((const ushort*)hraw);
        int b2 = b - PM_BLKS - CV_BLKS;
        int h = b2 >> 2, kq = b2 & 3;
        int o = t & 63, sub = t >> 6;
        int kbase = kq * 128 + sub * 32;
        uint pk[16];
#pragma unroll
        for (int kk = 0; kk < 32; kk += 2) {
            float v0, v1;
            size_t s0 = ((size_t)h * FIN + kbase + kk) * FOUT + o;
            size_t s1 = s0 + FOUT;
            if (isbf) { v0 = bf2f(((const ushort*)Wraw)[s0]); v1 = bf2f(((const ushort*)Wraw)[s1]); }
            else      { v0 = ((const float*)Wraw)[s0];        v1 = ((const float*)Wraw)[s1]; }
            pk[kk >> 1] = (uint)f2bf(v0) | ((uint)f2bf(v1) << 16);
        }
        ushort* dst = WT + ((size_t)h * FOUT + o) * FIN + kbase;
#pragma unroll
        for (int q = 0; q < 4; q++)
            *(uint4*)(dst + q * 8) = make_uint4(pk[q*4], pk[q*4+1], pk[q*4+2], pk[q*4+3]);
    }
}

// per-head tables: Kh = max_j er'; v_j = e^{er-Kh}; z_j = e^{alpha(er-Kh)}
__global__ __launch_bounds__(256) void khv_kernel(const float* __restrict__ er,
                                                  float* __restrict__ Kh,
                                                  float* __restrict__ vt,
                                                  float* __restrict__ zt) {
    __shared__ float red[256];
    int h = blockIdx.x >> 3, sl = blockIdx.x & 7, t = threadIdx.x;
    float m = -3.0e38f;
    for (int j = t; j < NN; j += 256) m = fmaxf(m, er[(size_t)h * NN + j]);
    red[t] = m;
    __syncthreads();
    for (int s = 128; s >= 1; s >>= 1) {
        if (t < s) red[t] = fmaxf(red[t], red[t + s]);
        __syncthreads();
    }
    float kh = red[0];
    if (t == 0 && sl == 0) Kh[h] = kh;
    int j = sl * 512 + t;
#pragma unroll
    for (int q = 0; q < 2; q++, j += 256) {
        float d = er[(size_t)h * NN + j] - kh;
        vt[(size_t)h * NN + j] = __expf(d);
        zt[(size_t)h * NN + j] = __expf(ALPHA * d);
    }
}

// ---------------------------------------------------------------------------
// Stage 1 (MFMA): Wh = h*W + bW; WhT[h][o][n] bf16; el/er dots (unchanged)
// ---------------------------------------------------------------------------
__global__ __launch_bounds__(256) void wh_kernel(
    const ushort* __restrict__ hmat, const ushort* __restrict__ WT,
    const void* __restrict__ bWr, const void* __restrict__ alr,
    const void* __restrict__ arr, const void* __restrict__ bAr,
    const ushort* __restrict__ hraw,
    ushort* __restrict__ WhT, float* __restrict__ el, float* __restrict__ er)
{
    __shared__ __align__(16) ushort sT[64][72];
    const int t = threadIdx.x, lane = t & 63, wid = t >> 6;
    const int head = blockIdx.y, rbase = blockIdx.x * 64;
    const int lm = lane & 15, lq = lane >> 4;

    floatx4 C[4];
#pragma unroll
    for (int cg = 0; cg < 4; cg++) C[cg] = (floatx4){0.f, 0.f, 0.f, 0.f};

    const ushort* Ap = hmat + (size_t)(rbase + wid * 16 + lm) * FIN + lq * 8;
    const ushort* Bp = WT + (size_t)head * FOUT * FIN + (size_t)lm * FIN + lq * 8;

#pragma unroll
    for (int kc = 0; kc < 16; kc++) {
        short8 a = *(const short8*)(Ap + kc * 32);
#pragma unroll
        for (int cg = 0; cg < 4; cg++) {
            short8 b = *(const short8*)(Bp + (size_t)cg * 16 * FIN + kc * 32);
            C[cg] = __builtin_amdgcn_mfma_f32_16x16x32_bf16(a, b, C[cg], 0, 0, 0);
        }
    }

    const int isbf = detect_bf16(hraw);
    float bA = isbf ? bf2f(((const ushort*)bAr)[head]) : ((const float*)bAr)[head];
    float pel[4] = {0.f, 0.f, 0.f, 0.f}, per[4] = {0.f, 0.f, 0.f, 0.f};
#pragma unroll
    for (int cg = 0; cg < 4; cg++) {
        int o = head * FOUT + cg * 16 + lm;
        float bw = isbf ? bf2f(((const ushort*)bWr)[o]) : ((const float*)bWr)[o];
        float av = isbf ? bf2f(((const ushort*)alr)[o]) : ((const float*)alr)[o];
        float rv = isbf ? bf2f(((const ushort*)arr)[o]) : ((const float*)arr)[o];
        ushort pk[4];
#pragma unroll
        for (int r = 0; r < 4; r++) {
            float v = C[cg][r] + bw;
            pel[r] += v * av;
            per[r] += v * rv;
            pk[r] = f2bf(v);
        }
        ushort4 p4; p4.x = pk[0]; p4.y = pk[1]; p4.z = pk[2]; p4.w = pk[3];
        *(ushort4*)(&sT[cg * 16 + lm][wid * 16 + lq * 4]) = p4;
    }
#pragma unroll
    for (int off = 1; off < 16; off <<= 1) {
#pragma unroll
        for (int r = 0; r < 4; r++) {
            pel[r] += __shfl_xor(pel[r], off);
            per[r] += __shfl_xor(per[r], off);
        }
    }
    if (lm == 0) {
#pragma unroll
        for (int r = 0; r < 4; r++) {
            int row = rbase + wid * 16 + lq * 4 + r;
            el[(size_t)head * NN + row] = pel[r];
            er[(size_t)head * NN + row] = per[r] + bA;
        }
    }
    __syncthreads();
    {
        int o = t >> 2, ch = t & 3;
        uint4 v0 = *(const uint4*)(&sT[o][ch * 16]);
        uint4 v1 = *(const uint4*)(&sT[o][ch * 16 + 8]);
        ushort* d = WhT + ((size_t)head * FOUT + o) * NN + rbase + ch * 16;
        *(uint4*)d = v0;
        *(uint4*)(d + 8) = v1;
    }
}

// ---------------------------------------------------------------------------
// Stage 2 (R18): BARRIER-FREE attn. Evidence: R16 (-45% LDS instrs) and R17
// (2x waves) both neutral; VALUBusy pinned ~41% in every lockstep structure
// => correlated stalls at the per-tile barrier are the limiter, not any pipe.
// Fix: drop LDS B-staging entirely (WhT slice is 512KB, L2-resident) and read
// B fragments per-wave straight from L2. Main loop has ZERO barriers: waves
// slip freely, stalls de-correlate, compiler pipelines loads across tiles.
//  - grid 1024 = 128 rowgroups x 8 heads (head = b&7 keeps per-XCD locality);
//    block 256 thr = 4 waves; each wave: 32 i-rows x 1 j-quarter (16 tiles).
//  - two A row-groups per wave share every B read (halves B L2 traffic,
//    ~0.5GB total ~ 15 TB/s < 34.5 ceiling).
//  - one-time 4-way partial merge through LDS (33.8KB) + single barrier.
// ---------------------------------------------------------------------------
__device__ __forceinline__ uint ppair(float v0, float v1, float z0, float z1,
                                      uint m2, float ui, float wi) {
    float p0 = fmaxf(ui * v0, wi * z0);    // = e^{lrelu(s)-Mi} (alpha<1)
    float p1 = fmaxf(ui * v1, wi * z1);
    uint k0 = (uint)0 - (m2 & 1u);
    uint k1 = (uint)0 - ((m2 >> 1) & 1u);
    p0 = __uint_as_float(__float_as_uint(p0) & k0);
    p1 = __uint_as_float(__float_as_uint(p1) & k1);
    __hip_bfloat162 r = __float22bfloat162_rn(make_float2(p0, p1));
    return *(uint*)&r;
}

__device__ __forceinline__ short8 pgen8(float4 va, float4 vb, float4 za, float4 zb,
                                        uint mby, float ui, float wi) {
    union { uint4 u; short8 s; } c;
    c.u.x = ppair(va.x, va.y, za.x, za.y, mby,      ui, wi);
    c.u.y = ppair(va.z, va.w, za.z, za.w, mby >> 2, ui, wi);
    c.u.z = ppair(vb.x, vb.y, zb.x, zb.y, mby >> 4, ui, wi);
    c.u.w = ppair(vb.z, vb.w, zb.z, zb.w, mby >> 6, ui, wi);
    return c.s;
}

__global__ __launch_bounds__(256, 4) void attn_kernel(
    const uchar* __restrict__ mb,      // [NN][512] bitmask
    const ushort* __restrict__ WhT,    // [H][FOUT][NN] bf16
    const float* __restrict__ el, const float* __restrict__ Kh,
    const float* __restrict__ vt, const float* __restrict__ zt,
    const ushort* __restrict__ hraw,
    void* __restrict__ outv)
{
    __shared__ __align__(16) float mg[3][64 * 44];   // 33.8 KB merge buffer

    const int t = threadIdx.x, lane = t & 63, jq = t >> 6;   // wave = j-quarter
    const int b = blockIdx.x;
    const int head = b & 7;                 // XCD locality: one head per XCD set
    const int ibase = (b >> 3) * 32;        // 128 rowgroups of 32 rows
    const int lm = lane & 15, lq = lane >> 4;
    const int sh8 = lq * 8;

    // per-lane row constants for rows lm and lm+16 of this 32-row group
    const float kh = Kh[head];
    const int rowa = ibase + lm;
    const float xa = el[(size_t)head * NN + rowa] + kh;
    const float xb = el[(size_t)head * NN + rowa + 16] + kh;
    const float Ma = fmaxf(xa, ALPHA * xa);
    const float Mb = fmaxf(xb, ALPHA * xb);
    const float uia = __expf(xa - Ma), wia = __expf(ALPHA * xa - Ma);
    const float uib = __expf(xb - Mb), wib = __expf(ALPHA * xb - Mb);

    const int jbase = jq * 1024;           // this wave's j-quarter
    const ushort* gB = WhT + (size_t)head * FOUT * NN;       // + o*NN + j
    const float* gvt = vt + (size_t)head * NN + jbase;
    const float* gzt = zt + (size_t)head * NN + jbase;
    const uchar* mra = mb + (size_t)rowa * 512 + (jbase >> 3);
    const uchar* mrb = mra + 16 * 512;

    const short8 ones = {0x3F80, 0x3F80, 0x3F80, 0x3F80, 0x3F80, 0x3F80, 0x3F80, 0x3F80};
    floatx4 Z = {0.f, 0.f, 0.f, 0.f};
    floatx4 C0 = Z, C1 = Z, C2 = Z, C3 = Z, Cd0 = Z;
    floatx4 C4 = Z, C5 = Z, C6 = Z, C7 = Z, Cd1 = Z;

    // barrier-free main loop: 16 tiles of 64 j
#pragma unroll 2
    for (int tile = 0; tile < 16; ++tile) {
        const int j0 = jbase + tile * 64;      // global j of tile start
        const int jl = tile * 64;              // local offset into gvt/gzt
        uint2 mka = *(const uint2*)(mra + tile * 8);
        uint2 mkb = *(const uint2*)(mrb + tile * 8);
        uint m0a = (mka.x >> sh8) & 0xFFu;
        uint m1a = (mka.y >> sh8) & 0xFFu;
        uint m0b = (mkb.x >> sh8) & 0xFFu;
        uint m1b = (mkb.y >> sh8) & 0xFFu;

        // ---- half 0: j in [j0, j0+32) ----
        float4 va = *(const float4*)(gvt + jl + sh8);
        float4 vb = *(const float4*)(gvt + jl + sh8 + 4);
        float4 za = *(const float4*)(gzt + jl + sh8);
        float4 zb = *(const float4*)(gzt + jl + sh8 + 4);
        short8 b00 = *(const short8*)(gB + (size_t)(0  + lm) * NN + j0 + sh8);
        short8 b10 = *(const short8*)(gB + (size_t)(16 + lm) * NN + j0 + sh8);
        short8 b20 = *(const short8*)(gB + (size_t)(32 + lm) * NN + j0 + sh8);
        short8 b30 = *(const short8*)(gB + (size_t)(48 + lm) * NN + j0 + sh8);
        short8 a0 = pgen8(va, vb, za, zb, m0a, uia, wia);   // rows lm
        short8 a2 = pgen8(va, vb, za, zb, m0b, uib, wib);   // rows lm+16
        Cd0 = __builtin_amdgcn_mfma_f32_16x16x32_bf16(a0, ones, Cd0, 0, 0, 0);
        Cd1 = __builtin_amdgcn_mfma_f32_16x16x32_bf16(a2, ones, Cd1, 0, 0, 0);
        C0 = __builtin_amdgcn_mfma_f32_16x16x32_bf16(a0, b00, C0, 0, 0, 0);
        C4 = __builtin_amdgcn_mfma_f32_16x16x32_bf16(a2, b00, C4, 0, 0, 0);
        C1 = __builtin_amdgcn_mfma_f32_16x16x32_bf16(a0, b10, C1, 0, 0, 0);
        C5 = __builtin_amdgcn_mfma_f32_16x16x32_bf16(a2, b10, C5, 0, 0, 0);
        C2 = __builtin_amdgcn_mfma_f32_16x16x32_bf16(a0, b20, C2, 0, 0, 0);
        C6 = __builtin_amdgcn_mfma_f32_16x16x32_bf16(a2, b20, C6, 0, 0, 0);
        C3 = __builtin_amdgcn_mfma_f32_16x16x32_bf16(a0, b30, C3, 0, 0, 0);
        C7 = __builtin_amdgcn_mfma_f32_16x16x32_bf16(a2, b30, C7, 0, 0, 0);

        // ---- half 1: j in [j0+32, j0+64) ----
        float4 vc = *(const float4*)(gvt + jl + 32 + sh8);
        float4 vd = *(const float4*)(gvt + jl + 32 + sh8 + 4);
        float4 zc = *(const float4*)(gzt + jl + 32 + sh8);
        float4 zd = *(const float4*)(gzt + jl + 32 + sh8 + 4);
        short8 b01 = *(const short8*)(gB + (size_t)(0  + lm) * NN + j0 + 32 + sh8);
        short8 b11 = *(const short8*)(gB + (size_t)(16 + lm) * NN + j0 + 32 + sh8);
        short8 b21 = *(const short8*)(gB + (size_t)(32 + lm) * NN + j0 + 32 + sh8);
        short8 b31 = *(const short8*)(gB + (size_t)(48 + lm) * NN + j0 + 32 + sh8);
        short8 a1 = pgen8(vc, vd, zc, zd, m1a, uia, wia);
        short8 a3 = pgen8(vc, vd, zc, zd, m1b, uib, wib);
        Cd0 = __builtin_amdgcn_mfma_f32_16x16x32_bf16(a1, ones, Cd0, 0, 0, 0);
        Cd1 = __builtin_amdgcn_mfma_f32_16x16x32_bf16(a3, ones, Cd1, 0, 0, 0);
        C0 = __builtin_amdgcn_mfma_f32_16x16x32_bf16(a1, b01, C0, 0, 0, 0);
        C4 = __builtin_amdgcn_mfma_f32_16x16x32_bf16(a3, b01, C4, 0, 0, 0);
        C1 = __builtin_amdgcn_mfma_f32_16x16x32_bf16(a1, b11, C1, 0, 0, 0);
        C5 = __builtin_amdgcn_mfma_f32_16x16x32_bf16(a3, b11, C5, 0, 0, 0);
        C2 = __builtin_amdgcn_mfma_f32_16x16x32_bf16(a1, b21, C2, 0, 0, 0);
        C6 = __builtin_amdgcn_mfma_f32_16x16x32_bf16(a3, b21, C6, 0, 0, 0);
        C3 = __builtin_amdgcn_mfma_f32_16x16x32_bf16(a1, b31, C3, 0, 0, 0);
        C7 = __builtin_amdgcn_mfma_f32_16x16x32_bf16(a3, b31, C7, 0, 0, 0);
    }

    // one-time 4-way partial merge: jq=1..3 publish 40 floats/lane, jq=0 sums.
    // lane stride 44 dwords (16B-aligned); one-time conflicts are negligible.
    if (jq > 0) {
        float* p = &mg[jq - 1][lane * 44];
        *(floatx4*)(p + 0)  = C0;  *(floatx4*)(p + 4)  = C1;
        *(floatx4*)(p + 8)  = C2;  *(floatx4*)(p + 12) = C3;
        *(floatx4*)(p + 16) = C4;  *(floatx4*)(p + 20) = C5;
        *(floatx4*)(p + 24) = C6;  *(floatx4*)(p + 28) = C7;
        *(floatx4*)(p + 32) = Cd0; *(floatx4*)(p + 36) = Cd1;
    }
    __syncthreads();
    if (jq == 0) {
#pragma unroll
        for (int s = 0; s < 3; s++) {
            const float* p = &mg[s][lane * 44];
            C0 += *(const floatx4*)(p + 0);   C1 += *(const floatx4*)(p + 4);
            C2 += *(const floatx4*)(p + 8);   C3 += *(const floatx4*)(p + 12);
            C4 += *(const floatx4*)(p + 16);  C5 += *(const floatx4*)(p + 20);
            C6 += *(const floatx4*)(p + 24);  C7 += *(const floatx4*)(p + 28);
            Cd0 += *(const floatx4*)(p + 32); Cd1 += *(const floatx4*)(p + 36);
        }
        // epilogue: normalize, elu, store (two row groups per lane)
        const int isbf = detect_bf16(hraw);
#pragma unroll
        for (int r = 0; r < 4; r++) {
            int ra = ibase + lq * 4 + r;
            int rb = ra + 16;
            float inva = 1.f / Cd0[r];
            float invb = 1.f / Cd1[r];
            float x0 = C0[r] * inva; x0 = (x0 > 0.f) ? x0 : __expf(x0) - 1.f;
            float x1 = C1[r] * inva; x1 = (x1 > 0.f) ? x1 : __expf(x1) - 1.f;
            float x2 = C2[r] * inva; x2 = (x2 > 0.f) ? x2 : __expf(x2) - 1.f;
            float x3 = C3[r] * inva; x3 = (x3 > 0.f) ? x3 : __expf(x3) - 1.f;
            float y0 = C4[r] * invb; y0 = (y0 > 0.f) ? y0 : __expf(y0) - 1.f;
            float y1 = C5[r] * invb; y1 = (y1 > 0.f) ? y1 : __expf(y1) - 1.f;
            float y2 = C6[r] * invb; y2 = (y2 > 0.f) ? y2 : __expf(y2) - 1.f;
            float y3 = C7[r] * invb; y3 = (y3 > 0.f) ? y3 : __expf(y3) - 1.f;
            size_t basea = (size_t)ra * (NH * FOUT) + head * FOUT + lm;
            size_t baseb = (size_t)rb * (NH * FOUT) + head * FOUT + lm;
            if (isbf) {
                ushort* o = (ushort*)outv;
                o[basea + 0]  = f2bf(x0);
                o[basea + 16] = f2bf(x1);
                o[basea + 32] = f2bf(x2);
                o[basea + 48] = f2bf(x3);
                o[baseb + 0]  = f2bf(y0);
                o[baseb + 16] = f2bf(y1);
                o[baseb + 32] = f2bf(y2);
                o[baseb + 48] = f2bf(y3);
            } else {
                float* o = (float*)outv;
                o[basea + 0]  = x0;
                o[basea + 16] = x1;
                o[basea + 32] = x2;
                o[basea + 48] = x3;
                o[baseb + 0]  = y0;
                o[baseb + 16] = y1;
                o[baseb + 32] = y2;
                o[baseb + 48] = y3;
            }
        }
    }
}

extern "C" void kernel_launch(void* const* d_in, const int* in_sizes, int n_in,
                              void* d_out, int out_size, void* d_ws, size_t ws_size,
                              hipStream_t stream)
{
    const void* hraw = d_in[0];
    const int*  mask = (const int*)d_in[1];
    const void* Wraw = d_in[2];
    const void* bWr  = d_in[3];
    const void* alr  = d_in[4];
    const void* arr  = d_in[5];
    const void* bAr  = d_in[6];

    char* w = (char*)d_ws;
    ushort* bh   = (ushort*)w;                  w += (size_t)NN * FIN * 2;        // 4 MB
    ushort* WT   = (ushort*)w;                  w += (size_t)NH * FOUT * FIN * 2; // 512 KB
    ushort* WhT  = (ushort*)w;                  w += (size_t)NH * FOUT * NN * 2;  // 4 MB
    float*  el   = (float*)w;                   w += (size_t)NH * NN * 4;
    float*  er   = (float*)w;                   w += (size_t)NH * NN * 4;
    float*  Kh   = (float*)w;                   w += 64;
    float*  vt   = (float*)w;                   w += (size_t)NH * NN * 4;
    float*  zt   = (float*)w;                   w += (size_t)NH * NN * 4;
    uchar*  mb   = (uchar*)w;                   w += (size_t)NN * 512;            // 2 MB

    prep_kernel<<<PM_BLKS + CV_BLKS + TW_BLKS, 256, 0, stream>>>(
        mask, mb, hraw, bh, Wraw, WT);
    wh_kernel<<<dim3(NN / 64, NH), 256, 0, stream>>>(bh, WT, bWr, alr, arr, bAr,
                                                     (const ushort*)hraw, WhT, el, er);
    khv_kernel<<<64, 256, 0, stream>>>(er, Kh, vt, zt);
    attn_kernel<<<128 * NH, 256, 0, stream>>>(mb, WhT, el, Kh, vt, zt,
                                              (const ushort*)hraw, d_out);
}

// Round 8
// 195.928 us; speedup vs baseline: 1.1073x; 1.1073x over previous
//
#include <hip/hip_runtime.h>
#include <hip/hip_bf16.h>
#include <hip/hip_fp16.h>

#define NN 4096
#define FIN 512
#define FOUT 64
#define NH 8
#define ALPHA 0.2f
#define PSCALE 4096.0f   // 2^12 row-invariant P scale (C/Cd invariant)

typedef unsigned int uint;
typedef unsigned short ushort;
typedef unsigned char uchar;
typedef unsigned long long ull;
typedef __attribute__((ext_vector_type(8))) short short8;
typedef __attribute__((ext_vector_type(8))) _Float16 half8;
typedef __attribute__((ext_vector_type(4))) float floatx4;
typedef __attribute__((ext_vector_type(4))) uint uintx4;
typedef __attribute__((ext_vector_type(2))) uint uintx2;

__device__ __forceinline__ float bf2f(ushort s) { return __uint_as_float(((uint)s) << 16); }
__device__ __forceinline__ ushort f2bf(float f) {
    uint u = __float_as_uint(f);
    u += 0x7fffu + ((u >> 16) & 1u);   // RNE
    return (ushort)(u >> 16);
}
__device__ __forceinline__ ushort f2h(float f) {
    return __half_as_ushort(__float2half_rn(f));
}

// inline dtype probe: wave-uniform, deterministic (same 64 samples everywhere)
__device__ __forceinline__ int detect_bf16(const ushort* __restrict__ hraw) {
    int lane = threadIdx.x & 63;
    float a = fabsf(bf2f(hraw[2 * lane]));
    ull bal = __ballot(a >= 1e-3f && a <= 100.0f);
    return __popcll(bal) >= 32;
}

// ---------------------------------------------------------------------------
// Fused prep: [0,8192) packmask | [8192,9216) convert h (8 elem/thread) |
//             [9216,9248) transw   (unchanged from passing rounds)
// ---------------------------------------------------------------------------
#define PM_BLKS 8192
#define CV_BLKS 1024
#define TW_BLKS 32

__global__ __launch_bounds__(256) void prep_kernel(
    const int* __restrict__ mask, uchar* __restrict__ mb,
    const void* __restrict__ hraw, ushort* __restrict__ bh,
    const void* __restrict__ Wraw, ushort* __restrict__ WT)
{
    const int b = blockIdx.x, t = threadIdx.x;
    if (b < PM_BLKS) {
        size_t gid = (size_t)b * 256 + t;
        const int* p = mask + gid * 8;
        int4 aa = *(const int4*)p;
        int4 bb = *(const int4*)(p + 4);
        uint by = (uint)(aa.x > 0)        | ((uint)(aa.y > 0) << 1)
                | ((uint)(aa.z > 0) << 2) | ((uint)(aa.w > 0) << 3)
                | ((uint)(bb.x > 0) << 4) | ((uint)(bb.y > 0) << 5)
                | ((uint)(bb.z > 0) << 6) | ((uint)(bb.w > 0) << 7);
        mb[gid] = (uchar)by;
    } else if (b < PM_BLKS + CV_BLKS) {
        int isbf = detect_bf16((const ushort*)hraw);
        size_t e0 = ((size_t)(b - PM_BLKS) * 256 + t) * 8;
        if (isbf) {
            *(uint4*)(bh + e0) = *(const uint4*)((const ushort*)hraw + e0);
        } else {
            const float* s = (const float*)hraw + e0;
            float4 f0 = *(const float4*)s;
            float4 f1 = *(const float4*)(s + 4);
            uint4 o;
            o.x = (uint)f2bf(f0.x) | ((uint)f2bf(f0.y) << 16);
            o.y = (uint)f2bf(f0.z) | ((uint)f2bf(f0.w) << 16);
            o.z = (uint)f2bf(f1.x) | ((uint)f2bf(f1.y) << 16);
            o.w = (uint)f2bf(f1.z) | ((uint)f2bf(f1.w) << 16);
            *(uint4*)(bh + e0) = o;
        }
    } else {
        int isbf = detect_bf16((const ushort*)hraw);
        int b2 = b - PM_BLKS - CV_BLKS;
        int h = b2 >> 2, kq = b2 & 3;
        int o = t & 63, sub = t >> 6;
        int kbase = kq * 128 + sub * 32;
        uint pk[16];
#pragma unroll
        for (int kk = 0; kk < 32; kk += 2) {
            float v0, v1;
            size_t s0 = ((size_t)h * FIN + kbase + kk) * FOUT + o;
            size_t s1 = s0 + FOUT;
            if (isbf) { v0 = bf2f(((const ushort*)Wraw)[s0]); v1 = bf2f(((const ushort*)Wraw)[s1]); }
            else      { v0 = ((const float*)Wraw)[s0];        v1 = ((const float*)Wraw)[s1]; }
            pk[kk >> 1] = (uint)f2bf(v0) | ((uint)f2bf(v1) << 16);
        }
        ushort* dst = WT + ((size_t)h * FOUT + o) * FIN + kbase;
#pragma unroll
        for (int q = 0; q < 4; q++)
            *(uint4*)(dst + q * 8) = make_uint4(pk[q*4], pk[q*4+1], pk[q*4+2], pk[q*4+3]);
    }
}

// per-head tables (fp16): Kh = max_j er'; v_j = e^{er-Kh}; z_j = e^{alpha(er-Kh)}
__global__ __launch_bounds__(256) void khv_kernel(const float* __restrict__ er,
                                                  float* __restrict__ Kh,
                                                  ushort* __restrict__ vt,
                                                  ushort* __restrict__ zt) {
    __shared__ float red[256];
    int h = blockIdx.x >> 3, sl = blockIdx.x & 7, t = threadIdx.x;
    float m = -3.0e38f;
    for (int j = t; j < NN; j += 256) m = fmaxf(m, er[(size_t)h * NN + j]);
    red[t] = m;
    __syncthreads();
    for (int s = 128; s >= 1; s >>= 1) {
        if (t < s) red[t] = fmaxf(red[t], red[t + s]);
        __syncthreads();
    }
    float kh = red[0];
    if (t == 0 && sl == 0) Kh[h] = kh;
    int j = sl * 512 + t;
#pragma unroll
    for (int q = 0; q < 2; q++, j += 256) {
        float d = er[(size_t)h * NN + j] - kh;
        vt[(size_t)h * NN + j] = f2h(__expf(d));
        zt[(size_t)h * NN + j] = f2h(__expf(ALPHA * d));
    }
}

// ---------------------------------------------------------------------------
// Stage 1 (MFMA): Wh = h*W + bW; WhT[h][o][n] now fp16; el/er dots (f32)
// ---------------------------------------------------------------------------
__global__ __launch_bounds__(256) void wh_kernel(
    const ushort* __restrict__ hmat, const ushort* __restrict__ WT,
    const void* __restrict__ bWr, const void* __restrict__ alr,
    const void* __restrict__ arr, const void* __restrict__ bAr,
    const ushort* __restrict__ hraw,
    ushort* __restrict__ WhT, float* __restrict__ el, float* __restrict__ er)
{
    __shared__ __align__(16) ushort sT[64][72];
    const int t = threadIdx.x, lane = t & 63, wid = t >> 6;
    const int head = blockIdx.y, rbase = blockIdx.x * 64;
    const int lm = lane & 15, lq = lane >> 4;

    floatx4 C[4];
#pragma unroll
    for (int cg = 0; cg < 4; cg++) C[cg] = (floatx4){0.f, 0.f, 0.f, 0.f};

    const ushort* Ap = hmat + (size_t)(rbase + wid * 16 + lm) * FIN + lq * 8;
    const ushort* Bp = WT + (size_t)head * FOUT * FIN + (size_t)lm * FIN + lq * 8;

#pragma unroll
    for (int kc = 0; kc < 16; kc++) {
        short8 a = *(const short8*)(Ap + kc * 32);
#pragma unroll
        for (int cg = 0; cg < 4; cg++) {
            short8 b = *(const short8*)(Bp + (size_t)cg * 16 * FIN + kc * 32);
            C[cg] = __builtin_amdgcn_mfma_f32_16x16x32_bf16(a, b, C[cg], 0, 0, 0);
        }
    }

    const int isbf = detect_bf16(hraw);
    float bA = isbf ? bf2f(((const ushort*)bAr)[head]) : ((const float*)bAr)[head];
    float pel[4] = {0.f, 0.f, 0.f, 0.f}, per[4] = {0.f, 0.f, 0.f, 0.f};
#pragma unroll
    for (int cg = 0; cg < 4; cg++) {
        int o = head * FOUT + cg * 16 + lm;
        float bw = isbf ? bf2f(((const ushort*)bWr)[o]) : ((const float*)bWr)[o];
        float av = isbf ? bf2f(((const ushort*)alr)[o]) : ((const float*)alr)[o];
        float rv = isbf ? bf2f(((const ushort*)arr)[o]) : ((const float*)arr)[o];
        ushort pk[4];
#pragma unroll
        for (int r = 0; r < 4; r++) {
            float v = C[cg][r] + bw;
            pel[r] += v * av;
            per[r] += v * rv;
            pk[r] = f2h(v);                    // fp16 WhT for stage 2
        }
        ushort4 p4; p4.x = pk[0]; p4.y = pk[1]; p4.z = pk[2]; p4.w = pk[3];
        *(ushort4*)(&sT[cg * 16 + lm][wid * 16 + lq * 4]) = p4;
    }
#pragma unroll
    for (int off = 1; off < 16; off <<= 1) {
#pragma unroll
        for (int r = 0; r < 4; r++) {
            pel[r] += __shfl_xor(pel[r], off);
            per[r] += __shfl_xor(per[r], off);
        }
    }
    if (lm == 0) {
#pragma unroll
        for (int r = 0; r < 4; r++) {
            int row = rbase + wid * 16 + lq * 4 + r;
            el[(size_t)head * NN + row] = pel[r];
            er[(size_t)head * NN + row] = per[r] + bA;
        }
    }
    __syncthreads();
    {
        int o = t >> 2, ch = t & 3;
        uint4 v0 = *(const uint4*)(&sT[o][ch * 16]);
        uint4 v1 = *(const uint4*)(&sT[o][ch * 16 + 8]);
        ushort* d = WhT + ((size_t)head * FOUT + o) * NN + rbase + ch * 16;
        *(uint4*)d = v0;
        *(uint4*)(d + 8) = v1;
    }
}

// ---------------------------------------------------------------------------
// Stage 2 (R21 = R20 with pmask2 fixed): R16 skeleton + fp16 packed P-gen +
// keep-alive pinning. BUGFIX: pmask2 must clamp to bits 0-1 BEFORE the
// bit-spread — (a | a<<15) let a's own bit16 (mask of j+16) corrupt the
// odd-element mask (R20's 1.35 absmax). Also fold PSCALE=2^12 into ui/wi
// (C/Cd ratio invariant) to keep P products out of fp16 subnormal range.
// ---------------------------------------------------------------------------
__device__ __forceinline__ uint pkmul(uint a, uint b) {
    uint d; asm("v_pk_mul_f16 %0,%1,%2" : "=v"(d) : "v"(a), "v"(b)); return d;
}
__device__ __forceinline__ uint pkmax(uint a, uint b) {
    uint d; asm("v_pk_max_f16 %0,%1,%2" : "=v"(d) : "v"(a), "v"(b)); return d;
}
// bits 0,1 of a -> 0x0000FFFF / 0xFFFF0000 select words
__device__ __forceinline__ uint pmask2(uint a) {
    uint b = a & 3u;
    return ((b | (b << 15)) & 0x10001u) * 0xFFFFu;
}
__device__ __forceinline__ half8 pgen8h(uintx4 vv, uintx4 zz, uint mby,
                                        uint uip, uint wip) {
    union { uintx4 u; half8 h; } c;
    c.u.x = pkmax(pkmul(uip, vv.x), pkmul(wip, zz.x)) & pmask2(mby);
    c.u.y = pkmax(pkmul(uip, vv.y), pkmul(wip, zz.y)) & pmask2(mby >> 2);
    c.u.z = pkmax(pkmul(uip, vv.z), pkmul(wip, zz.z)) & pmask2(mby >> 4);
    c.u.w = pkmax(pkmul(uip, vv.w), pkmul(wip, zz.w)) & pmask2(mby >> 6);
    return c.h;
}

#define KEEP(x) asm volatile("" : "+v"(x))

#define VZLOAD(S, j0) do {                                   \
    v##S##a = *(const uintx4*)(gvt + (j0) + sh8);            \
    v##S##b = *(const uintx4*)(gvt + (j0) + 32 + sh8);       \
    z##S##a = *(const uintx4*)(gzt + (j0) + sh8);            \
    z##S##b = *(const uintx4*)(gzt + (j0) + 32 + sh8);       \
} while (0)

__global__ __launch_bounds__(256, 2) void attn_kernel(
    const uchar* __restrict__ mb,      // [NN][512] bitmask
    const ushort* __restrict__ WhT,    // [H][FOUT][NN] fp16
    const float* __restrict__ el, const float* __restrict__ Kh,
    const ushort* __restrict__ vt, const ushort* __restrict__ zt,
    const ushort* __restrict__ hraw,
    void* __restrict__ outv)
{
    __shared__ __align__(16) ushort sB[2][64 * 72];  // B tile [o][j], dbuf

    const int t = threadIdx.x, lane = t & 63, wid = t >> 6;  // 4 waves
    const int b = blockIdx.x;
    const int head = b & 7;                       // XCD swizzle
    const int ibase = (b >> 3) * 64;
    const int lm = lane & 15, lq = lane >> 4;
    const int sh8 = lq * 8;

    // per-lane row constants, packed fp16 broadcast (PSCALE folded in)
    const float kh = Kh[head];
    const int row = ibase + wid * 16 + lm;
    const float x = el[(size_t)head * NN + row] + kh;
    const float Mi = fmaxf(x, ALPHA * x);
    const uint uip = (uint)f2h(PSCALE * __expf(x - Mi)) * 0x10001u;
    const uint wip = (uint)f2h(PSCALE * __expf(ALPHA * x - Mi)) * 0x10001u;

    // staging assignment: thread t -> B row so, col group sc (32 B = 2 uint4)
    const int so = t >> 2;
    const int sc = (t & 3) * 16;
    const ushort* gB = WhT + ((size_t)head * FOUT + so) * NN + sc;
    const ushort* gvt = vt + (size_t)head * NN;
    const ushort* gzt = zt + (size_t)head * NN;
    const uchar* mrow = mb + (size_t)row * 512;

    uintx4 rr0, rr1;
    uintx2 mk_s;

    auto gload = [&](int j0) {
        rr0 = *(const uintx4*)(gB + j0);
        rr1 = *(const uintx4*)(gB + j0 + 8);
        mk_s = *(const uintx2*)(mrow + (j0 >> 3));
    };
    auto lwrite = [&](int buf) {
        ushort* d = &sB[buf][so * 72 + sc];
        *(uintx4*)(d)     = rr0;
        *(uintx4*)(d + 8) = rr1;
    };

    uintx4 v0a, v0b, z0a, z0b;
    uintx4 v1a, v1b, z1a, z1b;

    const half8 onesh = {(_Float16)1.f, (_Float16)1.f, (_Float16)1.f, (_Float16)1.f,
                         (_Float16)1.f, (_Float16)1.f, (_Float16)1.f, (_Float16)1.f};
    floatx4 Z = {0.f, 0.f, 0.f, 0.f};
    floatx4 C0 = Z, C1 = Z, C2 = Z, C3 = Z, Cd = Z;

    auto compute = [&](int buf, uintx2 mk,
                       uintx4 vA, uintx4 vB, uintx4 zA, uintx4 zB) {
        uint m0 = mk.x >> sh8;
        uint m1 = mk.y >> sh8;
        half8 a0 = pgen8h(vA, zA, m0, uip, wip);   // j in [0,32)
        half8 a1 = pgen8h(vB, zB, m1, uip, wip);   // j in [32,64)
        const ushort* base = &sB[buf][0];
        half8 b00 = *(const half8*)(base + (0  + lm) * 72 + sh8);
        half8 b10 = *(const half8*)(base + (16 + lm) * 72 + sh8);
        half8 b20 = *(const half8*)(base + (32 + lm) * 72 + sh8);
        half8 b30 = *(const half8*)(base + (48 + lm) * 72 + sh8);
        Cd = __builtin_amdgcn_mfma_f32_16x16x32_f16(a0, onesh, Cd, 0, 0, 0);
        C0 = __builtin_amdgcn_mfma_f32_16x16x32_f16(a0, b00, C0, 0, 0, 0);
        C1 = __builtin_amdgcn_mfma_f32_16x16x32_f16(a0, b10, C1, 0, 0, 0);
        C2 = __builtin_amdgcn_mfma_f32_16x16x32_f16(a0, b20, C2, 0, 0, 0);
        C3 = __builtin_amdgcn_mfma_f32_16x16x32_f16(a0, b30, C3, 0, 0, 0);
        half8 b01 = *(const half8*)(base + (0  + lm) * 72 + 32 + sh8);
        half8 b11 = *(const half8*)(base + (16 + lm) * 72 + 32 + sh8);
        half8 b21 = *(const half8*)(base + (32 + lm) * 72 + 32 + sh8);
        half8 b31 = *(const half8*)(base + (48 + lm) * 72 + 32 + sh8);
        Cd = __builtin_amdgcn_mfma_f32_16x16x32_f16(a1, onesh, Cd, 0, 0, 0);
        C0 = __builtin_amdgcn_mfma_f32_16x16x32_f16(a1, b01, C0, 0, 0, 0);
        C1 = __builtin_amdgcn_mfma_f32_16x16x32_f16(a1, b11, C1, 0, 0, 0);
        C2 = __builtin_amdgcn_mfma_f32_16x16x32_f16(a1, b21, C2, 0, 0, 0);
        C3 = __builtin_amdgcn_mfma_f32_16x16x32_f16(a1, b31, C3, 0, 0, 0);
    };

    // prologue: buf0 <- B(0); rr <- B(1); vz0 <- tile 0
    uintx2 mk0, mk1;
    gload(0);
    lwrite(0);
    mk0 = mk_s;
    gload(64);
    VZLOAD(0, 0);
    KEEP(rr0); KEEP(rr1); KEEP(mk_s);
    KEEP(v0a); KEEP(v0b); KEEP(z0a); KEEP(z0b);
    __syncthreads();

    // main loop: 1 barrier per tile; prefetch issued before compute, pinned
    // live by KEEPs so its vmcnt wait lands after compute.
    for (int it = 0; it < 64; it += 2) {
        // phase A: compute tile it (buf0, vz0)
        lwrite(1);                               // B(it+1) -> buf1
        mk1 = mk_s;                              // masks(it+1)
        gload(((it + 2) & 63) * 64);             // rr <- B(it+2)
        VZLOAD(1, (it + 1) * 64);                // vz1 <- tile it+1
        compute(0, mk0, v0a, v0b, z0a, z0b);
        KEEP(v1a); KEEP(v1b); KEEP(z1a); KEEP(z1b);
        KEEP(rr0); KEEP(rr1); KEEP(mk_s);
        __syncthreads();
        // phase B: compute tile it+1 (buf1, vz1)
        lwrite(0);                               // B(it+2) -> buf0
        mk0 = mk_s;                              // masks(it+2)
        gload(((it + 3) & 63) * 64);             // rr <- B(it+3)
        VZLOAD(0, ((it + 2) & 63) * 64);         // vz0 <- tile it+2
        compute(1, mk1, v1a, v1b, z1a, z1b);
        KEEP(v0a); KEEP(v0b); KEEP(z0a); KEEP(z0b);
        KEEP(rr0); KEEP(rr1); KEEP(mk_s);
        __syncthreads();
    }

    // epilogue: normalize, elu, store
    const int isbf = detect_bf16(hraw);
#pragma unroll
    for (int r = 0; r < 4; r++) {
        int orow = ibase + wid * 16 + lq * 4 + r;
        float inv = 1.f / Cd[r];
        float x0 = C0[r] * inv; x0 = (x0 > 0.f) ? x0 : __expf(x0) - 1.f;
        float x1 = C1[r] * inv; x1 = (x1 > 0.f) ? x1 : __expf(x1) - 1.f;
        float x2 = C2[r] * inv; x2 = (x2 > 0.f) ? x2 : __expf(x2) - 1.f;
        float x3 = C3[r] * inv; x3 = (x3 > 0.f) ? x3 : __expf(x3) - 1.f;
        size_t base = (size_t)orow * (NH * FOUT) + head * FOUT + lm;
        if (isbf) {
            ushort* o = (ushort*)outv;
            o[base + 0]  = f2bf(x0);
            o[base + 16] = f2bf(x1);
            o[base + 32] = f2bf(x2);
            o[base + 48] = f2bf(x3);
        } else {
            float* o = (float*)outv;
            o[base + 0]  = x0;
            o[base + 16] = x1;
            o[base + 32] = x2;
            o[base + 48] = x3;
        }
    }
}

extern "C" void kernel_launch(void* const* d_in, const int* in_sizes, int n_in,
                              void* d_out, int out_size, void* d_ws, size_t ws_size,
                              hipStream_t stream)
{
    const void* hraw = d_in[0];
    const int*  mask = (const int*)d_in[1];
    const void* Wraw = d_in[2];
    const void* bWr  = d_in[3];
    const void* alr  = d_in[4];
    const void* arr  = d_in[5];
    const void* bAr  = d_in[6];

    char* w = (char*)d_ws;
    ushort* bh   = (ushort*)w;                  w += (size_t)NN * FIN * 2;        // 4 MB
    ushort* WT   = (ushort*)w;                  w += (size_t)NH * FOUT * FIN * 2; // 512 KB
    ushort* WhT  = (ushort*)w;                  w += (size_t)NH * FOUT * NN * 2;  // 4 MB
    float*  el   = (float*)w;                   w += (size_t)NH * NN * 4;
    float*  er   = (float*)w;                   w += (size_t)NH * NN * 4;
    float*  Kh   = (float*)w;                   w += 64;
    ushort* vt   = (ushort*)w;                  w += (size_t)NH * NN * 4;  // fp16, slack kept
    ushort* zt   = (ushort*)w;                  w += (size_t)NH * NN * 4;
    uchar*  mb   = (uchar*)w;                   w += (size_t)NN * 512;            // 2 MB

    prep_kernel<<<PM_BLKS + CV_BLKS + TW_BLKS, 256, 0, stream>>>(
        mask, mb, hraw, bh, Wraw, WT);
    wh_kernel<<<dim3(NN / 64, NH), 256, 0, stream>>>(bh, WT, bWr, alr, arr, bAr,
                                                     (const ushort*)hraw, WhT, el, er);
    khv_kernel<<<64, 256, 0, stream>>>(er, Kh, vt, zt);
    attn_kernel<<<NN / 64 * NH, 256, 0, stream>>>(mb, WhT, el, Kh, vt, zt,
                                                  (const ushort*)hraw, d_out);
}

// Round 9
// 180.238 us; speedup vs baseline: 1.2037x; 1.0870x over previous
//
#include <hip/hip_runtime.h>
#include <hip/hip_bf16.h>
#include <hip/hip_fp16.h>

#define NN 4096
#define FIN 512
#define FOUT 64
#define NH 8
#define ALPHA 0.2f
#define PSCALE 4096.0f   // 2^12 row-invariant P scale (C/Cd invariant)

typedef unsigned int uint;
typedef unsigned short ushort;
typedef unsigned char uchar;
typedef unsigned long long ull;
typedef __attribute__((ext_vector_type(8))) short short8;
typedef __attribute__((ext_vector_type(8))) _Float16 half8;
typedef __attribute__((ext_vector_type(4))) float floatx4;
typedef __attribute__((ext_vector_type(4))) uint uintx4;
typedef __attribute__((ext_vector_type(2))) uint uintx2;

__device__ __forceinline__ float bf2f(ushort s) { return __uint_as_float(((uint)s) << 16); }
__device__ __forceinline__ ushort f2bf(float f) {
    uint u = __float_as_uint(f);
    u += 0x7fffu + ((u >> 16) & 1u);   // RNE
    return (ushort)(u >> 16);
}
__device__ __forceinline__ ushort f2h(float f) {
    return __half_as_ushort(__float2half_rn(f));
}

// inline dtype probe: wave-uniform, deterministic (same 64 samples everywhere)
__device__ __forceinline__ int detect_bf16(const ushort* __restrict__ hraw) {
    int lane = threadIdx.x & 63;
    float a = fabsf(bf2f(hraw[2 * lane]));
    ull bal = __ballot(a >= 1e-3f && a <= 100.0f);
    return __popcll(bal) >= 32;
}

// ---------------------------------------------------------------------------
// Fused prep: [0,8192) packmask | [8192,9216) convert h (8 elem/thread) |
//             [9216,9248) transw   (unchanged from passing rounds)
// ---------------------------------------------------------------------------
#define PM_BLKS 8192
#define CV_BLKS 1024
#define TW_BLKS 32

__global__ __launch_bounds__(256) void prep_kernel(
    const int* __restrict__ mask, uchar* __restrict__ mb,
    const void* __restrict__ hraw, ushort* __restrict__ bh,
    const void* __restrict__ Wraw, ushort* __restrict__ WT)
{
    const int b = blockIdx.x, t = threadIdx.x;
    if (b < PM_BLKS) {
        size_t gid = (size_t)b * 256 + t;
        const int* p = mask + gid * 8;
        int4 aa = *(const int4*)p;
        int4 bb = *(const int4*)(p + 4);
        uint by = (uint)(aa.x > 0)        | ((uint)(aa.y > 0) << 1)
                | ((uint)(aa.z > 0) << 2) | ((uint)(aa.w > 0) << 3)
                | ((uint)(bb.x > 0) << 4) | ((uint)(bb.y > 0) << 5)
                | ((uint)(bb.z > 0) << 6) | ((uint)(bb.w > 0) << 7);
        mb[gid] = (uchar)by;
    } else if (b < PM_BLKS + CV_BLKS) {
        int isbf = detect_bf16((const ushort*)hraw);
        size_t e0 = ((size_t)(b - PM_BLKS) * 256 + t) * 8;
        if (isbf) {
            *(uint4*)(bh + e0) = *(const uint4*)((const ushort*)hraw + e0);
        } else {
            const float* s = (const float*)hraw + e0;
            float4 f0 = *(const float4*)s;
            float4 f1 = *(const float4*)(s + 4);
            uint4 o;
            o.x = (uint)f2bf(f0.x) | ((uint)f2bf(f0.y) << 16);
            o.y = (uint)f2bf(f0.z) | ((uint)f2bf(f0.w) << 16);
            o.z = (uint)f2bf(f1.x) | ((uint)f2bf(f1.y) << 16);
            o.w = (uint)f2bf(f1.z) | ((uint)f2bf(f1.w) << 16);
            *(uint4*)(bh + e0) = o;
        }
    } else {
        int isbf = detect_bf16((const ushort*)hraw);
        int b2 = b - PM_BLKS - CV_BLKS;
        int h = b2 >> 2, kq = b2 & 3;
        int o = t & 63, sub = t >> 6;
        int kbase = kq * 128 + sub * 32;
        uint pk[16];
#pragma unroll
        for (int kk = 0; kk < 32; kk += 2) {
            float v0, v1;
            size_t s0 = ((size_t)h * FIN + kbase + kk) * FOUT + o;
            size_t s1 = s0 + FOUT;
            if (isbf) { v0 = bf2f(((const ushort*)Wraw)[s0]); v1 = bf2f(((const ushort*)Wraw)[s1]); }
            else      { v0 = ((const float*)Wraw)[s0];        v1 = ((const float*)Wraw)[s1]; }
            pk[kk >> 1] = (uint)f2bf(v0) | ((uint)f2bf(v1) << 16);
        }
        ushort* dst = WT + ((size_t)h * FOUT + o) * FIN + kbase;
#pragma unroll
        for (int q = 0; q < 4; q++)
            *(uint4*)(dst + q * 8) = make_uint4(pk[q*4], pk[q*4+1], pk[q*4+2], pk[q*4+3]);
    }
}

// per-head tables (fp16): Kh = max_j er'; v_j = e^{er-Kh}; z_j = e^{alpha(er-Kh)}
__global__ __launch_bounds__(256) void khv_kernel(const float* __restrict__ er,
                                                  float* __restrict__ Kh,
                                                  ushort* __restrict__ vt,
                                                  ushort* __restrict__ zt) {
    __shared__ float red[256];
    int h = blockIdx.x >> 3, sl = blockIdx.x & 7, t = threadIdx.x;
    float m = -3.0e38f;
    for (int j = t; j < NN; j += 256) m = fmaxf(m, er[(size_t)h * NN + j]);
    red[t] = m;
    __syncthreads();
    for (int s = 128; s >= 1; s >>= 1) {
        if (t < s) red[t] = fmaxf(red[t], red[t + s]);
        __syncthreads();
    }
    float kh = red[0];
    if (t == 0 && sl == 0) Kh[h] = kh;
    int j = sl * 512 + t;
#pragma unroll
    for (int q = 0; q < 2; q++, j += 256) {
        float d = er[(size_t)h * NN + j] - kh;
        vt[(size_t)h * NN + j] = f2h(__expf(d));
        zt[(size_t)h * NN + j] = f2h(__expf(ALPHA * d));
    }
}

// ---------------------------------------------------------------------------
// Stage 1 (MFMA): Wh = h*W + bW; WhT[h][o][n] fp16; el/er dots (f32)
// ---------------------------------------------------------------------------
__global__ __launch_bounds__(256) void wh_kernel(
    const ushort* __restrict__ hmat, const ushort* __restrict__ WT,
    const void* __restrict__ bWr, const void* __restrict__ alr,
    const void* __restrict__ arr, const void* __restrict__ bAr,
    const ushort* __restrict__ hraw,
    ushort* __restrict__ WhT, float* __restrict__ el, float* __restrict__ er)
{
    __shared__ __align__(16) ushort sT[64][72];
    const int t = threadIdx.x, lane = t & 63, wid = t >> 6;
    const int head = blockIdx.y, rbase = blockIdx.x * 64;
    const int lm = lane & 15, lq = lane >> 4;

    floatx4 C[4];
#pragma unroll
    for (int cg = 0; cg < 4; cg++) C[cg] = (floatx4){0.f, 0.f, 0.f, 0.f};

    const ushort* Ap = hmat + (size_t)(rbase + wid * 16 + lm) * FIN + lq * 8;
    const ushort* Bp = WT + (size_t)head * FOUT * FIN + (size_t)lm * FIN + lq * 8;

#pragma unroll
    for (int kc = 0; kc < 16; kc++) {
        short8 a = *(const short8*)(Ap + kc * 32);
#pragma unroll
        for (int cg = 0; cg < 4; cg++) {
            short8 b = *(const short8*)(Bp + (size_t)cg * 16 * FIN + kc * 32);
            C[cg] = __builtin_amdgcn_mfma_f32_16x16x32_bf16(a, b, C[cg], 0, 0, 0);
        }
    }

    const int isbf = detect_bf16(hraw);
    float bA = isbf ? bf2f(((const ushort*)bAr)[head]) : ((const float*)bAr)[head];
    float pel[4] = {0.f, 0.f, 0.f, 0.f}, per[4] = {0.f, 0.f, 0.f, 0.f};
#pragma unroll
    for (int cg = 0; cg < 4; cg++) {
        int o = head * FOUT + cg * 16 + lm;
        float bw = isbf ? bf2f(((const ushort*)bWr)[o]) : ((const float*)bWr)[o];
        float av = isbf ? bf2f(((const ushort*)alr)[o]) : ((const float*)alr)[o];
        float rv = isbf ? bf2f(((const ushort*)arr)[o]) : ((const float*)arr)[o];
        ushort pk[4];
#pragma unroll
        for (int r = 0; r < 4; r++) {
            float v = C[cg][r] + bw;
            pel[r] += v * av;
            per[r] += v * rv;
            pk[r] = f2h(v);                    // fp16 WhT for stage 2
        }
        ushort4 p4; p4.x = pk[0]; p4.y = pk[1]; p4.z = pk[2]; p4.w = pk[3];
        *(ushort4*)(&sT[cg * 16 + lm][wid * 16 + lq * 4]) = p4;
    }
#pragma unroll
    for (int off = 1; off < 16; off <<= 1) {
#pragma unroll
        for (int r = 0; r < 4; r++) {
            pel[r] += __shfl_xor(pel[r], off);
            per[r] += __shfl_xor(per[r], off);
        }
    }
    if (lm == 0) {
#pragma unroll
        for (int r = 0; r < 4; r++) {
            int row = rbase + wid * 16 + lq * 4 + r;
            el[(size_t)head * NN + row] = pel[r];
            er[(size_t)head * NN + row] = per[r] + bA;
        }
    }
    __syncthreads();
    {
        int o = t >> 2, ch = t & 3;
        uint4 v0 = *(const uint4*)(&sT[o][ch * 16]);
        uint4 v1 = *(const uint4*)(&sT[o][ch * 16 + 8]);
        ushort* d = WhT + ((size_t)head * FOUT + o) * NN + rbase + ch * 16;
        *(uint4*)d = v0;
        *(uint4*)(d + 8) = v1;
    }
}

// ---------------------------------------------------------------------------
// Stage 2 (R22): phase-count halving. Diagnosis across R0/R16/R17/R21: every
// pipe has slack (LDS 50%, VALU 26%, MFMA 12%) yet wall/phase is invariant
// ~2430 cyc -> limiter is per-phase FIXED cost (barrier skew + exposed
// latency tails), paid 64x. This round pays it 32x:
//  - 4 waves = 2 row-groups x 2 j-halves; each wave: 32 i-rows (2 A-frags
//    share every B read, R14/R18-proven) x one j-half (32 tiles of 64).
//  - two B-tiles staged per phase (one per half, by 128 thr each);
//    barriers per block: 64 -> 32. LDS instr/block: -40%.
//  - fp16 packed P-gen + PSCALE + keep-alive pinning (R21-proven).
//  - one-time j-half merge through LDS (R17/R18-proven), then epilogue.
// ---------------------------------------------------------------------------
__device__ __forceinline__ uint pkmul(uint a, uint b) {
    uint d; asm("v_pk_mul_f16 %0,%1,%2" : "=v"(d) : "v"(a), "v"(b)); return d;
}
__device__ __forceinline__ uint pkmax(uint a, uint b) {
    uint d; asm("v_pk_max_f16 %0,%1,%2" : "=v"(d) : "v"(a), "v"(b)); return d;
}
// bits 0,1 of a -> 0x0000FFFF / 0xFFFF0000 select words
__device__ __forceinline__ uint pmask2(uint a) {
    uint b = a & 3u;
    return ((b | (b << 15)) & 0x10001u) * 0xFFFFu;
}
__device__ __forceinline__ half8 pgen8h(uintx4 vv, uintx4 zz, uint mby,
                                        uint uip, uint wip) {
    union { uintx4 u; half8 h; } c;
    c.u.x = pkmax(pkmul(uip, vv.x), pkmul(wip, zz.x)) & pmask2(mby);
    c.u.y = pkmax(pkmul(uip, vv.y), pkmul(wip, zz.y)) & pmask2(mby >> 2);
    c.u.z = pkmax(pkmul(uip, vv.z), pkmul(wip, zz.z)) & pmask2(mby >> 4);
    c.u.w = pkmax(pkmul(uip, vv.w), pkmul(wip, zz.w)) & pmask2(mby >> 6);
    return c.h;
}

#define KEEP(x) asm volatile("" : "+v"(x))

#define VZLOAD(S, j0) do {                                   \
    v##S##a = *(const uintx4*)(gvt + (j0) + sh8);            \
    v##S##b = *(const uintx4*)(gvt + (j0) + 32 + sh8);       \
    z##S##a = *(const uintx4*)(gzt + (j0) + sh8);            \
    z##S##b = *(const uintx4*)(gzt + (j0) + 32 + sh8);       \
} while (0)

__global__ __launch_bounds__(256, 2) void attn_kernel(
    const uchar* __restrict__ mb,      // [NN][512] bitmask
    const ushort* __restrict__ WhT,    // [H][FOUT][NN] fp16
    const float* __restrict__ el, const float* __restrict__ Kh,
    const ushort* __restrict__ vt, const ushort* __restrict__ zt,
    const ushort* __restrict__ hraw,
    void* __restrict__ outv)
{
    __shared__ __align__(16) ushort sB[2][2][64 * 72];  // [jhalf][dbuf] tiles

    const int t = threadIdx.x, lane = t & 63, wid = t >> 6;  // 4 waves
    const int rg = wid >> 1;       // row group (32 rows each)
    const int jh = wid & 1;        // j half (0: j<2048, 1: j>=2048)
    const int b = blockIdx.x;
    const int head = b & 7;                       // XCD swizzle
    const int ibase = (b >> 3) * 64;
    const int lm = lane & 15, lq = lane >> 4;
    const int sh8 = lq * 8;

    // per-lane row constants for rows lm and lm+16 of this wave's 32 rows
    const float kh = Kh[head];
    const int rowa = ibase + rg * 32 + lm;
    const float xa = el[(size_t)head * NN + rowa] + kh;
    const float xb = el[(size_t)head * NN + rowa + 16] + kh;
    const float Ma = fmaxf(xa, ALPHA * xa);
    const float Mb = fmaxf(xb, ALPHA * xb);
    const uint uipa = (uint)f2h(PSCALE * __expf(xa - Ma)) * 0x10001u;
    const uint wipa = (uint)f2h(PSCALE * __expf(ALPHA * xa - Ma)) * 0x10001u;
    const uint uipb = (uint)f2h(PSCALE * __expf(xb - Mb)) * 0x10001u;
    const uint wipb = (uint)f2h(PSCALE * __expf(ALPHA * xb - Mb)) * 0x10001u;

    // staging: the 128 threads of each j-half stage that half's tile.
    // st in [0,128): so = B row, sc = 64B col group (2 thr per row).
    const int jb = jh * 2048;
    const int st = rg * 64 + lane;
    const int so = st >> 1;
    const int sc = (st & 1) * 32;
    const ushort* gB = WhT + ((size_t)head * FOUT + so) * NN + jb + sc;
    const ushort* gvt = vt + (size_t)head * NN + jb;
    const ushort* gzt = zt + (size_t)head * NN + jb;
    const uchar* mra = mb + (size_t)rowa * 512 + (jb >> 3);
    const uchar* mrb = mra + 16 * 512;

    uintx4 rr0, rr1, rr2, rr3;
    uintx2 mka_s, mkb_s;

    auto gload = [&](int j0) {     // j0 local to this half, in [0,2048)
        rr0 = *(const uintx4*)(gB + j0);
        rr1 = *(const uintx4*)(gB + j0 + 8);
        rr2 = *(const uintx4*)(gB + j0 + 16);
        rr3 = *(const uintx4*)(gB + j0 + 24);
        mka_s = *(const uintx2*)(mra + (j0 >> 3));
        mkb_s = *(const uintx2*)(mrb + (j0 >> 3));
    };
    auto lwrite = [&](int buf) {
        ushort* d = &sB[jh][buf][so * 72 + sc];
        *(uintx4*)(d)      = rr0;
        *(uintx4*)(d + 8)  = rr1;
        *(uintx4*)(d + 16) = rr2;
        *(uintx4*)(d + 24) = rr3;
    };

    uintx4 v0a, v0b, z0a, z0b;
    uintx4 v1a, v1b, z1a, z1b;

    const half8 onesh = {(_Float16)1.f, (_Float16)1.f, (_Float16)1.f, (_Float16)1.f,
                         (_Float16)1.f, (_Float16)1.f, (_Float16)1.f, (_Float16)1.f};
    floatx4 Z = {0.f, 0.f, 0.f, 0.f};
    floatx4 C0 = Z, C1 = Z, C2 = Z, C3 = Z, Cd0 = Z;
    floatx4 C4 = Z, C5 = Z, C6 = Z, C7 = Z, Cd1 = Z;

    auto compute = [&](int buf, uintx2 mka, uintx2 mkb,
                       uintx4 vA, uintx4 vB, uintx4 zA, uintx4 zB) {
        uint m0a = mka.x >> sh8;
        uint m1a = mka.y >> sh8;
        uint m0b = mkb.x >> sh8;
        uint m1b = mkb.y >> sh8;
        half8 a0 = pgen8h(vA, zA, m0a, uipa, wipa);   // rows lm,    j 0..31
        half8 a1 = pgen8h(vB, zB, m1a, uipa, wipa);   // rows lm,    j 32..63
        half8 a2 = pgen8h(vA, zA, m0b, uipb, wipb);   // rows lm+16, j 0..31
        half8 a3 = pgen8h(vB, zB, m1b, uipb, wipb);   // rows lm+16, j 32..63
        const ushort* base = &sB[jh][buf][0];
        half8 b00 = *(const half8*)(base + (0  + lm) * 72 + sh8);
        half8 b10 = *(const half8*)(base + (16 + lm) * 72 + sh8);
        half8 b20 = *(const half8*)(base + (32 + lm) * 72 + sh8);
        half8 b30 = *(const half8*)(base + (48 + lm) * 72 + sh8);
        Cd0 = __builtin_amdgcn_mfma_f32_16x16x32_f16(a0, onesh, Cd0, 0, 0, 0);
        Cd1 = __builtin_amdgcn_mfma_f32_16x16x32_f16(a2, onesh, Cd1, 0, 0, 0);
        C0 = __builtin_amdgcn_mfma_f32_16x16x32_f16(a0, b00, C0, 0, 0, 0);
        C4 = __builtin_amdgcn_mfma_f32_16x16x32_f16(a2, b00, C4, 0, 0, 0);
        C1 = __builtin_amdgcn_mfma_f32_16x16x32_f16(a0, b10, C1, 0, 0, 0);
        C5 = __builtin_amdgcn_mfma_f32_16x16x32_f16(a2, b10, C5, 0, 0, 0);
        C2 = __builtin_amdgcn_mfma_f32_16x16x32_f16(a0, b20, C2, 0, 0, 0);
        C6 = __builtin_amdgcn_mfma_f32_16x16x32_f16(a2, b20, C6, 0, 0, 0);
        C3 = __builtin_amdgcn_mfma_f32_16x16x32_f16(a0, b30, C3, 0, 0, 0);
        C7 = __builtin_amdgcn_mfma_f32_16x16x32_f16(a2, b30, C7, 0, 0, 0);
        half8 b01 = *(const half8*)(base + (0  + lm) * 72 + 32 + sh8);
        half8 b11 = *(const half8*)(base + (16 + lm) * 72 + 32 + sh8);
        half8 b21 = *(const half8*)(base + (32 + lm) * 72 + 32 + sh8);
        half8 b31 = *(const half8*)(base + (48 + lm) * 72 + 32 + sh8);
        Cd0 = __builtin_amdgcn_mfma_f32_16x16x32_f16(a1, onesh, Cd0, 0, 0, 0);
        Cd1 = __builtin_amdgcn_mfma_f32_16x16x32_f16(a3, onesh, Cd1, 0, 0, 0);
        C0 = __builtin_amdgcn_mfma_f32_16x16x32_f16(a1, b01, C0, 0, 0, 0);
        C4 = __builtin_amdgcn_mfma_f32_16x16x32_f16(a3, b01, C4, 0, 0, 0);
        C1 = __builtin_amdgcn_mfma_f32_16x16x32_f16(a1, b11, C1, 0, 0, 0);
        C5 = __builtin_amdgcn_mfma_f32_16x16x32_f16(a3, b11, C5, 0, 0, 0);
        C2 = __builtin_amdgcn_mfma_f32_16x16x32_f16(a1, b21, C2, 0, 0, 0);
        C6 = __builtin_amdgcn_mfma_f32_16x16x32_f16(a3, b21, C6, 0, 0, 0);
        C3 = __builtin_amdgcn_mfma_f32_16x16x32_f16(a1, b31, C3, 0, 0, 0);
        C7 = __builtin_amdgcn_mfma_f32_16x16x32_f16(a3, b31, C7, 0, 0, 0);
    };

    // prologue: buf0 <- tile 0 of this half; rr <- tile 1; vz0 <- tile 0
    uintx2 mka0, mkb0, mka1, mkb1;
    gload(0);
    lwrite(0);
    mka0 = mka_s; mkb0 = mkb_s;
    gload(64);
    VZLOAD(0, 0);
    KEEP(rr0); KEEP(rr1); KEEP(rr2); KEEP(rr3);
    KEEP(v0a); KEEP(v0b); KEEP(z0a); KEEP(z0b);
    __syncthreads();

    // main loop: 32 tiles per wave, 1 barrier per tile; prefetch issued
    // before compute and pinned live so its wait lands after compute.
    for (int it = 0; it < 32; it += 2) {
        // phase A: compute tile it (buf0, vz0)
        lwrite(1);                               // tile it+1 -> buf1
        mka1 = mka_s; mkb1 = mkb_s;
        gload(((it + 2) & 31) * 64);             // rr <- tile it+2
        VZLOAD(1, (it + 1) * 64);                // vz1 <- tile it+1
        compute(0, mka0, mkb0, v0a, v0b, z0a, z0b);
        KEEP(v1a); KEEP(v1b); KEEP(z1a); KEEP(z1b);
        KEEP(rr0); KEEP(rr1); KEEP(rr2); KEEP(rr3);
        __syncthreads();
        // phase B: compute tile it+1 (buf1, vz1)
        lwrite(0);                               // tile it+2 -> buf0
        mka0 = mka_s; mkb0 = mkb_s;
        gload(((it + 3) & 31) * 64);             // rr <- tile it+3
        VZLOAD(0, ((it + 2) & 31) * 64);         // vz0 <- tile it+2
        compute(1, mka1, mkb1, v1a, v1b, z1a, z1b);
        KEEP(v0a); KEEP(v0b); KEEP(z0a); KEEP(z0b);
        KEEP(rr0); KEEP(rr1); KEEP(rr2); KEEP(rr3);
        __syncthreads();
    }

    // merge j-halves: jh=1 waves publish partials via LDS, jh=0 accumulate.
    // lane stride 44 dwords (16B-aligned, odd/4 stride -> spread banks).
    float* mg = (float*)&sB[0][0][0];   // 22528 B needed <= 36864 B
    const int mi = (rg * 64 + lane) * 44;
    if (jh == 1) {
        float* p = &mg[mi];
        *(floatx4*)(p + 0)  = C0;  *(floatx4*)(p + 4)  = C1;
        *(floatx4*)(p + 8)  = C2;  *(floatx4*)(p + 12) = C3;
        *(floatx4*)(p + 16) = C4;  *(floatx4*)(p + 20) = C5;
        *(floatx4*)(p + 24) = C6;  *(floatx4*)(p + 28) = C7;
        *(floatx4*)(p + 32) = Cd0; *(floatx4*)(p + 36) = Cd1;
    }
    __syncthreads();
    if (jh == 0) {
        const float* p = &mg[mi];
        C0 += *(const floatx4*)(p + 0);   C1 += *(const floatx4*)(p + 4);
        C2 += *(const floatx4*)(p + 8);   C3 += *(const floatx4*)(p + 12);
        C4 += *(const floatx4*)(p + 16);  C5 += *(const floatx4*)(p + 20);
        C6 += *(const floatx4*)(p + 24);  C7 += *(const floatx4*)(p + 28);
        Cd0 += *(const floatx4*)(p + 32); Cd1 += *(const floatx4*)(p + 36);

        // epilogue: normalize, elu, store (two row groups per lane)
        const int isbf = detect_bf16(hraw);
#pragma unroll
        for (int r = 0; r < 4; r++) {
            int ra = ibase + rg * 32 + lq * 4 + r;
            int rb = ra + 16;
            float inva = 1.f / Cd0[r];
            float invb = 1.f / Cd1[r];
            float x0 = C0[r] * inva; x0 = (x0 > 0.f) ? x0 : __expf(x0) - 1.f;
            float x1 = C1[r] * inva; x1 = (x1 > 0.f) ? x1 : __expf(x1) - 1.f;
            float x2 = C2[r] * inva; x2 = (x2 > 0.f) ? x2 : __expf(x2) - 1.f;
            float x3 = C3[r] * inva; x3 = (x3 > 0.f) ? x3 : __expf(x3) - 1.f;
            float y0 = C4[r] * invb; y0 = (y0 > 0.f) ? y0 : __expf(y0) - 1.f;
            float y1 = C5[r] * invb; y1 = (y1 > 0.f) ? y1 : __expf(y1) - 1.f;
            float y2 = C6[r] * invb; y2 = (y2 > 0.f) ? y2 : __expf(y2) - 1.f;
            float y3 = C7[r] * invb; y3 = (y3 > 0.f) ? y3 : __expf(y3) - 1.f;
            size_t basea = (size_t)ra * (NH * FOUT) + head * FOUT + lm;
            size_t baseb = (size_t)rb * (NH * FOUT) + head * FOUT + lm;
            if (isbf) {
                ushort* o = (ushort*)outv;
                o[basea + 0]  = f2bf(x0);
                o[basea + 16] = f2bf(x1);
                o[basea + 32] = f2bf(x2);
                o[basea + 48] = f2bf(x3);
                o[baseb + 0]  = f2bf(y0);
                o[baseb + 16] = f2bf(y1);
                o[baseb + 32] = f2bf(y2);
                o[baseb + 48] = f2bf(y3);
            } else {
                float* o = (float*)outv;
                o[basea + 0]  = x0;
                o[basea + 16] = x1;
                o[basea + 32] = x2;
                o[basea + 48] = x3;
                o[baseb + 0]  = y0;
                o[baseb + 16] = y1;
                o[baseb + 32] = y2;
                o[baseb + 48] = y3;
            }
        }
    }
}

extern "C" void kernel_launch(void* const* d_in, const int* in_sizes, int n_in,
                              void* d_out, int out_size, void* d_ws, size_t ws_size,
                              hipStream_t stream)
{
    const void* hraw = d_in[0];
    const int*  mask = (const int*)d_in[1];
    const void* Wraw = d_in[2];
    const void* bWr  = d_in[3];
    const void* alr  = d_in[4];
    const void* arr  = d_in[5];
    const void* bAr  = d_in[6];

    char* w = (char*)d_ws;
    ushort* bh   = (ushort*)w;                  w += (size_t)NN * FIN * 2;        // 4 MB
    ushort* WT   = (ushort*)w;                  w += (size_t)NH * FOUT * FIN * 2; // 512 KB
    ushort* WhT  = (ushort*)w;                  w += (size_t)NH * FOUT * NN * 2;  // 4 MB
    float*  el   = (float*)w;                   w += (size_t)NH * NN * 4;
    float*  er   = (float*)w;                   w += (size_t)NH * NN * 4;
    float*  Kh   = (float*)w;                   w += 64;
    ushort* vt   = (ushort*)w;                  w += (size_t)NH * NN * 4;  // fp16, slack kept
    ushort* zt   = (ushort*)w;                  w += (size_t)NH * NN * 4;
    uchar*  mb   = (uchar*)w;                   w += (size_t)NN * 512;            // 2 MB

    prep_kernel<<<PM_BLKS + CV_BLKS + TW_BLKS, 256, 0, stream>>>(
        mask, mb, hraw, bh, Wraw, WT);
    wh_kernel<<<dim3(NN / 64, NH), 256, 0, stream>>>(bh, WT, bWr, alr, arr, bAr,
                                                     (const ushort*)hraw, WhT, el, er);
    khv_kernel<<<64, 256, 0, stream>>>(er, Kh, vt, zt);
    attn_kernel<<<NN / 64 * NH, 256, 0, stream>>>(mb, WhT, el, Kh, vt, zt,
                                                  (const ushort*)hraw, d_out);
}

// Round 10
// 177.688 us; speedup vs baseline: 1.2210x; 1.0144x over previous
//
#include <hip/hip_runtime.h>
#include <hip/hip_bf16.h>
#include <hip/hip_fp16.h>

#define NN 4096
#define FIN 512
#define FOUT 64
#define NH 8
#define ALPHA 0.2f
#define PSCALE 4096.0f   // 2^12 row-invariant P scale (C/Cd invariant)

typedef unsigned int uint;
typedef unsigned short ushort;
typedef unsigned char uchar;
typedef unsigned long long ull;
typedef __attribute__((ext_vector_type(8))) short short8;
typedef __attribute__((ext_vector_type(8))) _Float16 half8;
typedef __attribute__((ext_vector_type(4))) float floatx4;
typedef __attribute__((ext_vector_type(4))) uint uintx4;
typedef __attribute__((ext_vector_type(2))) uint uintx2;

__device__ __forceinline__ float bf2f(ushort s) { return __uint_as_float(((uint)s) << 16); }
__device__ __forceinline__ ushort f2bf(float f) {
    uint u = __float_as_uint(f);
    u += 0x7fffu + ((u >> 16) & 1u);   // RNE
    return (ushort)(u >> 16);
}
__device__ __forceinline__ ushort f2h(float f) {
    return __half_as_ushort(__float2half_rn(f));
}

// inline dtype probe: wave-uniform, deterministic (same 64 samples everywhere)
__device__ __forceinline__ int detect_bf16(const ushort* __restrict__ hraw) {
    int lane = threadIdx.x & 63;
    float a = fabsf(bf2f(hraw[2 * lane]));
    ull bal = __ballot(a >= 1e-3f && a <= 100.0f);
    return __popcll(bal) >= 32;
}

// ---------------------------------------------------------------------------
// Fused prep: [0,8192) packmask | [8192,9216) convert h (8 elem/thread) |
//             [9216,9248) transw   (unchanged from passing rounds)
// ---------------------------------------------------------------------------
#define PM_BLKS 8192
#define CV_BLKS 1024
#define TW_BLKS 32

__global__ __launch_bounds__(256) void prep_kernel(
    const int* __restrict__ mask, uchar* __restrict__ mb,
    const void* __restrict__ hraw, ushort* __restrict__ bh,
    const void* __restrict__ Wraw, ushort* __restrict__ WT)
{
    const int b = blockIdx.x, t = threadIdx.x;
    if (b < PM_BLKS) {
        size_t gid = (size_t)b * 256 + t;
        const int* p = mask + gid * 8;
        int4 aa = *(const int4*)p;
        int4 bb = *(const int4*)(p + 4);
        uint by = (uint)(aa.x > 0)        | ((uint)(aa.y > 0) << 1)
                | ((uint)(aa.z > 0) << 2) | ((uint)(aa.w > 0) << 3)
                | ((uint)(bb.x > 0) << 4) | ((uint)(bb.y > 0) << 5)
                | ((uint)(bb.z > 0) << 6) | ((uint)(bb.w > 0) << 7);
        mb[gid] = (uchar)by;
    } else if (b < PM_BLKS + CV_BLKS) {
        int isbf = detect_bf16((const ushort*)hraw);
        size_t e0 = ((size_t)(b - PM_BLKS) * 256 + t) * 8;
        if (isbf) {
            *(uint4*)(bh + e0) = *(const uint4*)((const ushort*)hraw + e0);
        } else {
            const float* s = (const float*)hraw + e0;
            float4 f0 = *(const float4*)s;
            float4 f1 = *(const float4*)(s + 4);
            uint4 o;
            o.x = (uint)f2bf(f0.x) | ((uint)f2bf(f0.y) << 16);
            o.y = (uint)f2bf(f0.z) | ((uint)f2bf(f0.w) << 16);
            o.z = (uint)f2bf(f1.x) | ((uint)f2bf(f1.y) << 16);
            o.w = (uint)f2bf(f1.z) | ((uint)f2bf(f1.w) << 16);
            *(uint4*)(bh + e0) = o;
        }
    } else {
        int isbf = detect_bf16((const ushort*)hraw);
        int b2 = b - PM_BLKS - CV_BLKS;
        int h = b2 >> 2, kq = b2 & 3;
        int o = t & 63, sub = t >> 6;
        int kbase = kq * 128 + sub * 32;
        uint pk[16];
#pragma unroll
        for (int kk = 0; kk < 32; kk += 2) {
            float v0, v1;
            size_t s0 = ((size_t)h * FIN + kbase + kk) * FOUT + o;
            size_t s1 = s0 + FOUT;
            if (isbf) { v0 = bf2f(((const ushort*)Wraw)[s0]); v1 = bf2f(((const ushort*)Wraw)[s1]); }
            else      { v0 = ((const float*)Wraw)[s0];        v1 = ((const float*)Wraw)[s1]; }
            pk[kk >> 1] = (uint)f2bf(v0) | ((uint)f2bf(v1) << 16);
        }
        ushort* dst = WT + ((size_t)h * FOUT + o) * FIN + kbase;
#pragma unroll
        for (int q = 0; q < 4; q++)
            *(uint4*)(dst + q * 8) = make_uint4(pk[q*4], pk[q*4+1], pk[q*4+2], pk[q*4+3]);
    }
}

// per-head tables (fp16): Kh = max_j er'; v_j = e^{er-Kh}; z_j = e^{alpha(er-Kh)}
__global__ __launch_bounds__(256) void khv_kernel(const float* __restrict__ er,
                                                  float* __restrict__ Kh,
                                                  ushort* __restrict__ vt,
                                                  ushort* __restrict__ zt) {
    __shared__ float red[256];
    int h = blockIdx.x >> 3, sl = blockIdx.x & 7, t = threadIdx.x;
    float m = -3.0e38f;
    for (int j = t; j < NN; j += 256) m = fmaxf(m, er[(size_t)h * NN + j]);
    red[t] = m;
    __syncthreads();
    for (int s = 128; s >= 1; s >>= 1) {
        if (t < s) red[t] = fmaxf(red[t], red[t + s]);
        __syncthreads();
    }
    float kh = red[0];
    if (t == 0 && sl == 0) Kh[h] = kh;
    int j = sl * 512 + t;
#pragma unroll
    for (int q = 0; q < 2; q++, j += 256) {
        float d = er[(size_t)h * NN + j] - kh;
        vt[(size_t)h * NN + j] = f2h(__expf(d));
        zt[(size_t)h * NN + j] = f2h(__expf(ALPHA * d));
    }
}

// ---------------------------------------------------------------------------
// Stage 1 (MFMA): Wh = h*W + bW; WhT[h][o][n] fp16; el/er dots (f32)
// ---------------------------------------------------------------------------
__global__ __launch_bounds__(256) void wh_kernel(
    const ushort* __restrict__ hmat, const ushort* __restrict__ WT,
    const void* __restrict__ bWr, const void* __restrict__ alr,
    const void* __restrict__ arr, const void* __restrict__ bAr,
    const ushort* __restrict__ hraw,
    ushort* __restrict__ WhT, float* __restrict__ el, float* __restrict__ er)
{
    __shared__ __align__(16) ushort sT[64][72];
    const int t = threadIdx.x, lane = t & 63, wid = t >> 6;
    const int head = blockIdx.y, rbase = blockIdx.x * 64;
    const int lm = lane & 15, lq = lane >> 4;

    floatx4 C[4];
#pragma unroll
    for (int cg = 0; cg < 4; cg++) C[cg] = (floatx4){0.f, 0.f, 0.f, 0.f};

    const ushort* Ap = hmat + (size_t)(rbase + wid * 16 + lm) * FIN + lq * 8;
    const ushort* Bp = WT + (size_t)head * FOUT * FIN + (size_t)lm * FIN + lq * 8;

#pragma unroll
    for (int kc = 0; kc < 16; kc++) {
        short8 a = *(const short8*)(Ap + kc * 32);
#pragma unroll
        for (int cg = 0; cg < 4; cg++) {
            short8 b = *(const short8*)(Bp + (size_t)cg * 16 * FIN + kc * 32);
            C[cg] = __builtin_amdgcn_mfma_f32_16x16x32_bf16(a, b, C[cg], 0, 0, 0);
        }
    }

    const int isbf = detect_bf16(hraw);
    float bA = isbf ? bf2f(((const ushort*)bAr)[head]) : ((const float*)bAr)[head];
    float pel[4] = {0.f, 0.f, 0.f, 0.f}, per[4] = {0.f, 0.f, 0.f, 0.f};
#pragma unroll
    for (int cg = 0; cg < 4; cg++) {
        int o = head * FOUT + cg * 16 + lm;
        float bw = isbf ? bf2f(((const ushort*)bWr)[o]) : ((const float*)bWr)[o];
        float av = isbf ? bf2f(((const ushort*)alr)[o]) : ((const float*)alr)[o];
        float rv = isbf ? bf2f(((const ushort*)arr)[o]) : ((const float*)arr)[o];
        ushort pk[4];
#pragma unroll
        for (int r = 0; r < 4; r++) {
            float v = C[cg][r] + bw;
            pel[r] += v * av;
            per[r] += v * rv;
            pk[r] = f2h(v);                    // fp16 WhT for stage 2
        }
        ushort4 p4; p4.x = pk[0]; p4.y = pk[1]; p4.z = pk[2]; p4.w = pk[3];
        *(ushort4*)(&sT[cg * 16 + lm][wid * 16 + lq * 4]) = p4;
    }
#pragma unroll
    for (int off = 1; off < 16; off <<= 1) {
#pragma unroll
        for (int r = 0; r < 4; r++) {
            pel[r] += __shfl_xor(pel[r], off);
            per[r] += __shfl_xor(per[r], off);
        }
    }
    if (lm == 0) {
#pragma unroll
        for (int r = 0; r < 4; r++) {
            int row = rbase + wid * 16 + lq * 4 + r;
            el[(size_t)head * NN + row] = pel[r];
            er[(size_t)head * NN + row] = per[r] + bA;
        }
    }
    __syncthreads();
    {
        int o = t >> 2, ch = t & 3;
        uint4 v0 = *(const uint4*)(&sT[o][ch * 16]);
        uint4 v1 = *(const uint4*)(&sT[o][ch * 16 + 8]);
        ushort* d = WhT + ((size_t)head * FOUT + o) * NN + rbase + ch * 16;
        *(uint4*)d = v0;
        *(uint4*)(d + 8) = v1;
    }
}

// ---------------------------------------------------------------------------
// Stage 2 (R23 = R22 + counted barrier, T4): __syncthreads compiles to
// "s_waitcnt vmcnt(0) lgkmcnt(0); s_barrier" — it drains the 10 in-flight
// prefetch loads EVERY phase, putting their L2 latency into the per-phase
// fixed cost (the invariant ~1300 cyc R22 halved by phase-count). The barrier
// only needs LDS-write visibility: lgkmcnt(0) + raw s_barrier. Global loads
// target registers; the compiler places counted vmcnt waits at their use
// points, so loads stay in flight across the barrier (m218's mechanism).
// Double-buffer discipline identical to R22 (one barrier/phase, both
// directions preserved).
// ---------------------------------------------------------------------------
__device__ __forceinline__ uint pkmul(uint a, uint b) {
    uint d; asm("v_pk_mul_f16 %0,%1,%2" : "=v"(d) : "v"(a), "v"(b)); return d;
}
__device__ __forceinline__ uint pkmax(uint a, uint b) {
    uint d; asm("v_pk_max_f16 %0,%1,%2" : "=v"(d) : "v"(a), "v"(b)); return d;
}
// bits 0,1 of a -> 0x0000FFFF / 0xFFFF0000 select words
__device__ __forceinline__ uint pmask2(uint a) {
    uint b = a & 3u;
    return ((b | (b << 15)) & 0x10001u) * 0xFFFFu;
}
__device__ __forceinline__ half8 pgen8h(uintx4 vv, uintx4 zz, uint mby,
                                        uint uip, uint wip) {
    union { uintx4 u; half8 h; } c;
    c.u.x = pkmax(pkmul(uip, vv.x), pkmul(wip, zz.x)) & pmask2(mby);
    c.u.y = pkmax(pkmul(uip, vv.y), pkmul(wip, zz.y)) & pmask2(mby >> 2);
    c.u.z = pkmax(pkmul(uip, vv.z), pkmul(wip, zz.z)) & pmask2(mby >> 4);
    c.u.w = pkmax(pkmul(uip, vv.w), pkmul(wip, zz.w)) & pmask2(mby >> 6);
    return c.h;
}

#define KEEP(x) asm volatile("" : "+v"(x))
// counted barrier: LDS-write visibility only; vmcnt stays counted at use sites
#define BARRIER() do { asm volatile("s_waitcnt lgkmcnt(0)" ::: "memory"); \
                       __builtin_amdgcn_s_barrier(); } while (0)

#define VZLOAD(S, j0) do {                                   \
    v##S##a = *(const uintx4*)(gvt + (j0) + sh8);            \
    v##S##b = *(const uintx4*)(gvt + (j0) + 32 + sh8);       \
    z##S##a = *(const uintx4*)(gzt + (j0) + sh8);            \
    z##S##b = *(const uintx4*)(gzt + (j0) + 32 + sh8);       \
} while (0)

__global__ __launch_bounds__(256, 2) void attn_kernel(
    const uchar* __restrict__ mb,      // [NN][512] bitmask
    const ushort* __restrict__ WhT,    // [H][FOUT][NN] fp16
    const float* __restrict__ el, const float* __restrict__ Kh,
    const ushort* __restrict__ vt, const ushort* __restrict__ zt,
    const ushort* __restrict__ hraw,
    void* __restrict__ outv)
{
    __shared__ __align__(16) ushort sB[2][2][64 * 72];  // [jhalf][dbuf] tiles

    const int t = threadIdx.x, lane = t & 63, wid = t >> 6;  // 4 waves
    const int rg = wid >> 1;       // row group (32 rows each)
    const int jh = wid & 1;        // j half (0: j<2048, 1: j>=2048)
    const int b = blockIdx.x;
    const int head = b & 7;                       // XCD swizzle
    const int ibase = (b >> 3) * 64;
    const int lm = lane & 15, lq = lane >> 4;
    const int sh8 = lq * 8;

    // per-lane row constants for rows lm and lm+16 of this wave's 32 rows
    const float kh = Kh[head];
    const int rowa = ibase + rg * 32 + lm;
    const float xa = el[(size_t)head * NN + rowa] + kh;
    const float xb = el[(size_t)head * NN + rowa + 16] + kh;
    const float Ma = fmaxf(xa, ALPHA * xa);
    const float Mb = fmaxf(xb, ALPHA * xb);
    const uint uipa = (uint)f2h(PSCALE * __expf(xa - Ma)) * 0x10001u;
    const uint wipa = (uint)f2h(PSCALE * __expf(ALPHA * xa - Ma)) * 0x10001u;
    const uint uipb = (uint)f2h(PSCALE * __expf(xb - Mb)) * 0x10001u;
    const uint wipb = (uint)f2h(PSCALE * __expf(ALPHA * xb - Mb)) * 0x10001u;

    // staging: the 128 threads of each j-half stage that half's tile.
    // st in [0,128): so = B row, sc = 64B col group (2 thr per row).
    const int jb = jh * 2048;
    const int st = rg * 64 + lane;
    const int so = st >> 1;
    const int sc = (st & 1) * 32;
    const ushort* gB = WhT + ((size_t)head * FOUT + so) * NN + jb + sc;
    const ushort* gvt = vt + (size_t)head * NN + jb;
    const ushort* gzt = zt + (size_t)head * NN + jb;
    const uchar* mra = mb + (size_t)rowa * 512 + (jb >> 3);
    const uchar* mrb = mra + 16 * 512;

    uintx4 rr0, rr1, rr2, rr3;
    uintx2 mka_s, mkb_s;

    auto gload = [&](int j0) {     // j0 local to this half, in [0,2048)
        rr0 = *(const uintx4*)(gB + j0);
        rr1 = *(const uintx4*)(gB + j0 + 8);
        rr2 = *(const uintx4*)(gB + j0 + 16);
        rr3 = *(const uintx4*)(gB + j0 + 24);
        mka_s = *(const uintx2*)(mra + (j0 >> 3));
        mkb_s = *(const uintx2*)(mrb + (j0 >> 3));
    };
    auto lwrite = [&](int buf) {
        ushort* d = &sB[jh][buf][so * 72 + sc];
        *(uintx4*)(d)      = rr0;
        *(uintx4*)(d + 8)  = rr1;
        *(uintx4*)(d + 16) = rr2;
        *(uintx4*)(d + 24) = rr3;
    };

    uintx4 v0a, v0b, z0a, z0b;
    uintx4 v1a, v1b, z1a, z1b;

    const half8 onesh = {(_Float16)1.f, (_Float16)1.f, (_Float16)1.f, (_Float16)1.f,
                         (_Float16)1.f, (_Float16)1.f, (_Float16)1.f, (_Float16)1.f};
    floatx4 Z = {0.f, 0.f, 0.f, 0.f};
    floatx4 C0 = Z, C1 = Z, C2 = Z, C3 = Z, Cd0 = Z;
    floatx4 C4 = Z, C5 = Z, C6 = Z, C7 = Z, Cd1 = Z;

    auto compute = [&](int buf, uintx2 mka, uintx2 mkb,
                       uintx4 vA, uintx4 vB, uintx4 zA, uintx4 zB) {
        uint m0a = mka.x >> sh8;
        uint m1a = mka.y >> sh8;
        uint m0b = mkb.x >> sh8;
        uint m1b = mkb.y >> sh8;
        half8 a0 = pgen8h(vA, zA, m0a, uipa, wipa);   // rows lm,    j 0..31
        half8 a1 = pgen8h(vB, zB, m1a, uipa, wipa);   // rows lm,    j 32..63
        half8 a2 = pgen8h(vA, zA, m0b, uipb, wipb);   // rows lm+16, j 0..31
        half8 a3 = pgen8h(vB, zB, m1b, uipb, wipb);   // rows lm+16, j 32..63
        const ushort* base = &sB[jh][buf][0];
        half8 b00 = *(const half8*)(base + (0  + lm) * 72 + sh8);
        half8 b10 = *(const half8*)(base + (16 + lm) * 72 + sh8);
        half8 b20 = *(const half8*)(base + (32 + lm) * 72 + sh8);
        half8 b30 = *(const half8*)(base + (48 + lm) * 72 + sh8);
        Cd0 = __builtin_amdgcn_mfma_f32_16x16x32_f16(a0, onesh, Cd0, 0, 0, 0);
        Cd1 = __builtin_amdgcn_mfma_f32_16x16x32_f16(a2, onesh, Cd1, 0, 0, 0);
        C0 = __builtin_amdgcn_mfma_f32_16x16x32_f16(a0, b00, C0, 0, 0, 0);
        C4 = __builtin_amdgcn_mfma_f32_16x16x32_f16(a2, b00, C4, 0, 0, 0);
        C1 = __builtin_amdgcn_mfma_f32_16x16x32_f16(a0, b10, C1, 0, 0, 0);
        C5 = __builtin_amdgcn_mfma_f32_16x16x32_f16(a2, b10, C5, 0, 0, 0);
        C2 = __builtin_amdgcn_mfma_f32_16x16x32_f16(a0, b20, C2, 0, 0, 0);
        C6 = __builtin_amdgcn_mfma_f32_16x16x32_f16(a2, b20, C6, 0, 0, 0);
        C3 = __builtin_amdgcn_mfma_f32_16x16x32_f16(a0, b30, C3, 0, 0, 0);
        C7 = __builtin_amdgcn_mfma_f32_16x16x32_f16(a2, b30, C7, 0, 0, 0);
        half8 b01 = *(const half8*)(base + (0  + lm) * 72 + 32 + sh8);
        half8 b11 = *(const half8*)(base + (16 + lm) * 72 + 32 + sh8);
        half8 b21 = *(const half8*)(base + (32 + lm) * 72 + 32 + sh8);
        half8 b31 = *(const half8*)(base + (48 + lm) * 72 + 32 + sh8);
        Cd0 = __builtin_amdgcn_mfma_f32_16x16x32_f16(a1, onesh, Cd0, 0, 0, 0);
        Cd1 = __builtin_amdgcn_mfma_f32_16x16x32_f16(a3, onesh, Cd1, 0, 0, 0);
        C0 = __builtin_amdgcn_mfma_f32_16x16x32_f16(a1, b01, C0, 0, 0, 0);
        C4 = __builtin_amdgcn_mfma_f32_16x16x32_f16(a3, b01, C4, 0, 0, 0);
        C1 = __builtin_amdgcn_mfma_f32_16x16x32_f16(a1, b11, C1, 0, 0, 0);
        C5 = __builtin_amdgcn_mfma_f32_16x16x32_f16(a3, b11, C5, 0, 0, 0);
        C2 = __builtin_amdgcn_mfma_f32_16x16x32_f16(a1, b21, C2, 0, 0, 0);
        C6 = __builtin_amdgcn_mfma_f32_16x16x32_f16(a3, b21, C6, 0, 0, 0);
        C3 = __builtin_amdgcn_mfma_f32_16x16x32_f16(a1, b31, C3, 0, 0, 0);
        C7 = __builtin_amdgcn_mfma_f32_16x16x32_f16(a3, b31, C7, 0, 0, 0);
    };

    // prologue: buf0 <- tile 0 of this half; rr <- tile 1; vz0 <- tile 0
    uintx2 mka0, mkb0, mka1, mkb1;
    gload(0);
    lwrite(0);
    mka0 = mka_s; mkb0 = mkb_s;
    gload(64);
    VZLOAD(0, 0);
    KEEP(rr0); KEEP(rr1); KEEP(rr2); KEEP(rr3);
    KEEP(v0a); KEEP(v0b); KEEP(z0a); KEEP(z0b);
    BARRIER();

    // main loop: 32 tiles per wave, 1 counted barrier per tile; prefetch
    // issued before compute and pinned live; loads cross the barrier.
    for (int it = 0; it < 32; it += 2) {
        // phase A: compute tile it (buf0, vz0)
        lwrite(1);                               // tile it+1 -> buf1
        mka1 = mka_s; mkb1 = mkb_s;
        gload(((it + 2) & 31) * 64);             // rr <- tile it+2
        VZLOAD(1, (it + 1) * 64);                // vz1 <- tile it+1
        compute(0, mka0, mkb0, v0a, v0b, z0a, z0b);
        KEEP(v1a); KEEP(v1b); KEEP(z1a); KEEP(z1b);
        KEEP(rr0); KEEP(rr1); KEEP(rr2); KEEP(rr3);
        BARRIER();
        // phase B: compute tile it+1 (buf1, vz1)
        lwrite(0);                               // tile it+2 -> buf0
        mka0 = mka_s; mkb0 = mkb_s;
        gload(((it + 3) & 31) * 64);             // rr <- tile it+3
        VZLOAD(0, ((it + 2) & 31) * 64);         // vz0 <- tile it+2
        compute(1, mka1, mkb1, v1a, v1b, z1a, z1b);
        KEEP(v0a); KEEP(v0b); KEEP(z0a); KEEP(z0b);
        KEEP(rr0); KEEP(rr1); KEEP(rr2); KEEP(rr3);
        BARRIER();
    }

    // merge j-halves: jh=1 waves publish partials via LDS, jh=0 accumulate.
    // lane stride 44 dwords (16B-aligned, odd/4 stride -> spread banks).
    float* mg = (float*)&sB[0][0][0];   // 22528 B needed <= 36864 B
    const int mi = (rg * 64 + lane) * 44;
    if (jh == 1) {
        float* p = &mg[mi];
        *(floatx4*)(p + 0)  = C0;  *(floatx4*)(p + 4)  = C1;
        *(floatx4*)(p + 8)  = C2;  *(floatx4*)(p + 12) = C3;
        *(floatx4*)(p + 16) = C4;  *(floatx4*)(p + 20) = C5;
        *(floatx4*)(p + 24) = C6;  *(floatx4*)(p + 28) = C7;
        *(floatx4*)(p + 32) = Cd0; *(floatx4*)(p + 36) = Cd1;
    }
    BARRIER();
    if (jh == 0) {
        const float* p = &mg[mi];
        C0 += *(const floatx4*)(p + 0);   C1 += *(const floatx4*)(p + 4);
        C2 += *(const floatx4*)(p + 8);   C3 += *(const floatx4*)(p + 12);
        C4 += *(const floatx4*)(p + 16);  C5 += *(const floatx4*)(p + 20);
        C6 += *(const floatx4*)(p + 24);  C7 += *(const floatx4*)(p + 28);
        Cd0 += *(const floatx4*)(p + 32); Cd1 += *(const floatx4*)(p + 36);

        // epilogue: normalize, elu, store (two row groups per lane)
        const int isbf = detect_bf16(hraw);
#pragma unroll
        for (int r = 0; r < 4; r++) {
            int ra = ibase + rg * 32 + lq * 4 + r;
            int rb = ra + 16;
            float inva = 1.f / Cd0[r];
            float invb = 1.f / Cd1[r];
            float x0 = C0[r] * inva; x0 = (x0 > 0.f) ? x0 : __expf(x0) - 1.f;
            float x1 = C1[r] * inva; x1 = (x1 > 0.f) ? x1 : __expf(x1) - 1.f;
            float x2 = C2[r] * inva; x2 = (x2 > 0.f) ? x2 : __expf(x2) - 1.f;
            float x3 = C3[r] * inva; x3 = (x3 > 0.f) ? x3 : __expf(x3) - 1.f;
            float y0 = C4[r] * invb; y0 = (y0 > 0.f) ? y0 : __expf(y0) - 1.f;
            float y1 = C5[r] * invb; y1 = (y1 > 0.f) ? y1 : __expf(y1) - 1.f;
            float y2 = C6[r] * invb; y2 = (y2 > 0.f) ? y2 : __expf(y2) - 1.f;
            float y3 = C7[r] * invb; y3 = (y3 > 0.f) ? y3 : __expf(y3) - 1.f;
            size_t basea = (size_t)ra * (NH * FOUT) + head * FOUT + lm;
            size_t baseb = (size_t)rb * (NH * FOUT) + head * FOUT + lm;
            if (isbf) {
                ushort* o = (ushort*)outv;
                o[basea + 0]  = f2bf(x0);
                o[basea + 16] = f2bf(x1);
                o[basea + 32] = f2bf(x2);
                o[basea + 48] = f2bf(x3);
                o[baseb + 0]  = f2bf(y0);
                o[baseb + 16] = f2bf(y1);
                o[baseb + 32] = f2bf(y2);
                o[baseb + 48] = f2bf(y3);
            } else {
                float* o = (float*)outv;
                o[basea + 0]  = x0;
                o[basea + 16] = x1;
                o[basea + 32] = x2;
                o[basea + 48] = x3;
                o[baseb + 0]  = y0;
                o[baseb + 16] = y1;
                o[baseb + 32] = y2;
                o[baseb + 48] = y3;
            }
        }
    }
}

extern "C" void kernel_launch(void* const* d_in, const int* in_sizes, int n_in,
                              void* d_out, int out_size, void* d_ws, size_t ws_size,
                              hipStream_t stream)
{
    const void* hraw = d_in[0];
    const int*  mask = (const int*)d_in[1];
    const void* Wraw = d_in[2];
    const void* bWr  = d_in[3];
    const void* alr  = d_in[4];
    const void* arr  = d_in[5];
    const void* bAr  = d_in[6];

    char* w = (char*)d_ws;
    ushort* bh   = (ushort*)w;                  w += (size_t)NN * FIN * 2;        // 4 MB
    ushort* WT   = (ushort*)w;                  w += (size_t)NH * FOUT * FIN * 2; // 512 KB
    ushort* WhT  = (ushort*)w;                  w += (size_t)NH * FOUT * NN * 2;  // 4 MB
    float*  el   = (float*)w;                   w += (size_t)NH * NN * 4;
    float*  er   = (float*)w;                   w += (size_t)NH * NN * 4;
    float*  Kh   = (float*)w;                   w += 64;
    ushort* vt   = (ushort*)w;                  w += (size_t)NH * NN * 4;  // fp16, slack kept
    ushort* zt   = (ushort*)w;                  w += (size_t)NH * NN * 4;
    uchar*  mb   = (uchar*)w;                   w += (size_t)NN * 512;            // 2 MB

    prep_kernel<<<PM_BLKS + CV_BLKS + TW_BLKS, 256, 0, stream>>>(
        mask, mb, hraw, bh, Wraw, WT);
    wh_kernel<<<dim3(NN / 64, NH), 256, 0, stream>>>(bh, WT, bWr, alr, arr, bAr,
                                                     (const ushort*)hraw, WhT, el, er);
    khv_kernel<<<64, 256, 0, stream>>>(er, Kh, vt, zt);
    attn_kernel<<<NN / 64 * NH, 256, 0, stream>>>(mb, WhT, el, Kh, vt, zt,
                                                  (const ushort*)hraw, d_out);
}